// Round 1
// baseline (690.372 us; speedup 1.0000x reference)
//
#include <hip/hip_runtime.h>
#include <math.h>

#define NNODES 50000
#define NEDGES 800000
#define INDIM 256
#define HID 64
#define HEADS 4
#define OUTDIM 64
#define NEG_SLOPE 0.2f

// ---------------- CSR build ----------------

__global__ __launch_bounds__(256) void hist_kernel(const int* __restrict__ dst,
                                                   int* __restrict__ deg) {
    int i = blockIdx.x * 256 + threadIdx.x;
    if (i < NEDGES) atomicAdd(&deg[dst[i]], 1);
}

__global__ __launch_bounds__(1024) void scan_kernel(const int* __restrict__ deg,
                                                    int* __restrict__ offs) {
    const int n = NNODES;
    int t = threadIdx.x;
    int lane = t & 63, wid = t >> 6;
    const int per = (n + 1023) / 1024;  // 49
    int s0 = t * per;
    int sum = 0;
    for (int i = 0; i < per; ++i) { int idx = s0 + i; if (idx < n) sum += deg[idx]; }
    int v = sum;
    #pragma unroll
    for (int o = 1; o < 64; o <<= 1) { int u = __shfl_up(v, o); if (lane >= o) v += u; }
    __shared__ int wsum[16];
    if (lane == 63) wsum[wid] = v;
    __syncthreads();
    if (t < 16) {
        int wv = wsum[t];
        #pragma unroll
        for (int o = 1; o < 16; o <<= 1) { int u = __shfl_up(wv, o); if (t >= o) wv += u; }
        wsum[t] = wv;  // inclusive scan of wave sums
    }
    __syncthreads();
    int waveoff = (wid == 0) ? 0 : wsum[wid - 1];
    int run = waveoff + v - sum;  // exclusive prefix for this thread's chunk
    for (int i = 0; i < per; ++i) {
        int idx = s0 + i;
        if (idx < n) { offs[idx] = run; run += deg[idx]; }
    }
    if (t == 1023) offs[n] = run;  // total = NEDGES
}

__global__ __launch_bounds__(256) void scatter_kernel(const int* __restrict__ src,
                                                      const int* __restrict__ dst,
                                                      const int* __restrict__ offs,
                                                      int* __restrict__ cursor,
                                                      int* __restrict__ ssorted) {
    int i = blockIdx.x * 256 + threadIdx.x;
    if (i < NEDGES) {
        int d = dst[i];
        int pos = offs[d] + atomicAdd(&cursor[d], 1);
        ssorted[pos] = src[i];
    }
}

// ---------------- fp32 tiled GEMM: C[M,N] = A[M,K] @ B[K,N] ----------------
// BM=64, BN=64, BK=16, 256 threads, 4x4 microtile per thread.

__global__ __launch_bounds__(256) void gemm_kernel(const float* __restrict__ A,
                                                   const float* __restrict__ B,
                                                   float* __restrict__ C,
                                                   int M, int N, int K) {
    __shared__ float As[16][65];  // [k][m], padded
    __shared__ float Bs[16][64];  // [k][n]
    int t = threadIdx.x;
    int tx = t & 15, ty = t >> 4;
    int m0 = blockIdx.y * 64, n0 = blockIdx.x * 64;
    float acc[4][4] = {};
    for (int k0 = 0; k0 < K; k0 += 16) {
        #pragma unroll
        for (int i = 0; i < 4; ++i) {
            int li = t + i * 256;      // [64][16]: m=li>>4, k=li&15
            int m = li >> 4, k = li & 15;
            int gm = m0 + m;
            As[k][m] = (gm < M) ? A[(size_t)gm * K + k0 + k] : 0.f;
        }
        #pragma unroll
        for (int i = 0; i < 4; ++i) {
            int li = t + i * 256;      // [16][64]: k=li>>6, n=li&63
            int k = li >> 6, nn = li & 63;
            Bs[k][nn] = B[(size_t)(k0 + k) * N + n0 + nn];
        }
        __syncthreads();
        #pragma unroll
        for (int k = 0; k < 16; ++k) {
            float a[4], b[4];
            #pragma unroll
            for (int i = 0; i < 4; ++i) a[i] = As[k][ty * 4 + i];
            #pragma unroll
            for (int j = 0; j < 4; ++j) b[j] = Bs[k][tx * 4 + j];
            #pragma unroll
            for (int i = 0; i < 4; ++i)
                #pragma unroll
                for (int j = 0; j < 4; ++j)
                    acc[i][j] = fmaf(a[i], b[j], acc[i][j]);
        }
        __syncthreads();
    }
    #pragma unroll
    for (int i = 0; i < 4; ++i) {
        int gm = m0 + ty * 4 + i;
        if (gm < M) {
            #pragma unroll
            for (int j = 0; j < 4; ++j)
                C[(size_t)gm * N + n0 + tx * 4 + j] = acc[i][j];
        }
    }
}

// ---------------- attention coefficient dot products ----------------

__global__ __launch_bounds__(256) void elr1_kernel(const float* __restrict__ feat,
                                                   const float* __restrict__ al,
                                                   const float* __restrict__ ar,
                                                   float* __restrict__ el,
                                                   float* __restrict__ er) {
    int n = blockIdx.x;
    int t = threadIdx.x;         // t = h*64 + d
    int h = t >> 6, d = t & 63;
    float f = feat[(size_t)n * 256 + t];
    float a = f * al[t];
    float b = f * ar[t];
    #pragma unroll
    for (int o = 32; o; o >>= 1) { a += __shfl_xor(a, o); b += __shfl_xor(b, o); }
    if (d == 0) { el[n * HEADS + h] = a; er[n * HEADS + h] = b; }
}

__global__ __launch_bounds__(64) void elr2_kernel(const float* __restrict__ feat,
                                                  const float* __restrict__ al,
                                                  const float* __restrict__ ar,
                                                  float* __restrict__ el,
                                                  float* __restrict__ er) {
    int n = blockIdx.x, d = threadIdx.x;
    float f = feat[(size_t)n * 64 + d];
    float a = f * al[d], b = f * ar[d];
    #pragma unroll
    for (int o = 32; o; o >>= 1) { a += __shfl_xor(a, o); b += __shfl_xor(b, o); }
    if (d == 0) { el[n] = a; er[n] = b; }
}

// ---------------- per-node softmax aggregation (online softmax) ----------------
// Layer 1: block = 256 threads = 4 waves, wave h handles head h. Fused ELU.

__global__ __launch_bounds__(256) void agg1_kernel(const float* __restrict__ feat,
                                                   const float* __restrict__ el,
                                                   const float* __restrict__ er,
                                                   const int* __restrict__ offs,
                                                   const int* __restrict__ ssorted,
                                                   float* __restrict__ h1) {
    int n = blockIdx.x;
    int t = threadIdx.x;
    int h = t >> 6, d = t & 63;
    int start = offs[n], end = offs[n + 1];
    float ern = er[n * HEADS + h];
    float m = -INFINITY, s = 0.f, acc = 0.f;
    for (int base = start; base < end; base += 64) {
        int cnt = min(64, end - base);
        int sj = 0; float ej = -INFINITY;
        if (d < cnt) {
            sj = ssorted[base + d];
            float e = el[sj * HEADS + h] + ern;
            ej = (e > 0.f) ? e : NEG_SLOPE * e;
        }
        float cm = ej;
        #pragma unroll
        for (int o = 32; o; o >>= 1) cm = fmaxf(cm, __shfl_xor(cm, o));
        float nm = fmaxf(m, cm);
        float scale = (m > -INFINITY) ? __expf(m - nm) : 0.f;
        s *= scale; acc *= scale;
        for (int j = 0; j < cnt; ++j) {
            float e = __shfl(ej, j);
            int sn = __shfl(sj, j);
            float w = __expf(e - nm);
            s += w;
            acc = fmaf(w, feat[(size_t)sn * 256 + t], acc);
        }
        m = nm;
    }
    float v = (end > start) ? (acc / s) : 0.f;
    v = (v > 0.f) ? v : (__expf(v) - 1.f);   // ELU fused
    h1[(size_t)n * 256 + t] = v;
}

// Layer 2: one wave per node, H=1, D=64; writes logits directly (mean over 1 head).

__global__ __launch_bounds__(64) void agg2_kernel(const float* __restrict__ feat,
                                                  const float* __restrict__ el,
                                                  const float* __restrict__ er,
                                                  const int* __restrict__ offs,
                                                  const int* __restrict__ ssorted,
                                                  float* __restrict__ out) {
    int n = blockIdx.x;
    int d = threadIdx.x;
    int start = offs[n], end = offs[n + 1];
    float ern = er[n];
    float m = -INFINITY, s = 0.f, acc = 0.f;
    for (int base = start; base < end; base += 64) {
        int cnt = min(64, end - base);
        int sj = 0; float ej = -INFINITY;
        if (d < cnt) {
            sj = ssorted[base + d];
            float e = el[sj] + ern;
            ej = (e > 0.f) ? e : NEG_SLOPE * e;
        }
        float cm = ej;
        #pragma unroll
        for (int o = 32; o; o >>= 1) cm = fmaxf(cm, __shfl_xor(cm, o));
        float nm = fmaxf(m, cm);
        float scale = (m > -INFINITY) ? __expf(m - nm) : 0.f;
        s *= scale; acc *= scale;
        for (int j = 0; j < cnt; ++j) {
            float e = __shfl(ej, j);
            int sn = __shfl(sj, j);
            float w = __expf(e - nm);
            s += w;
            acc = fmaf(w, feat[(size_t)sn * 64 + d], acc);
        }
        m = nm;
    }
    out[(size_t)n * 64 + d] = (end > start) ? (acc / s) : 0.f;
}

// ---------------- launch ----------------

extern "C" void kernel_launch(void* const* d_in, const int* in_sizes, int n_in,
                              void* d_out, int out_size, void* d_ws, size_t ws_size,
                              hipStream_t stream) {
    const float* x   = (const float*)d_in[0];
    const int*   src = (const int*)d_in[1];
    const int*   dst = (const int*)d_in[2];
    const float* W1  = (const float*)d_in[3];
    const float* al1 = (const float*)d_in[4];
    const float* ar1 = (const float*)d_in[5];
    const float* W2  = (const float*)d_in[6];
    const float* al2 = (const float*)d_in[7];
    const float* ar2 = (const float*)d_in[8];
    float* out = (float*)d_out;

    char* ws = (char*)d_ws;
    size_t off = 0;
    auto alloc = [&](size_t bytes) -> void* {
        void* p = ws + off;
        off += (bytes + 255) & ~(size_t)255;
        return p;
    };
    float* feat1 = (float*)alloc((size_t)NNODES * 256 * 4);   // 51.2 MB
    float* h1    = (float*)alloc((size_t)NNODES * 256 * 4);   // 51.2 MB
    float* feat2 = (float*)alloc((size_t)NNODES * 64 * 4);    // 12.8 MB
    float* el1   = (float*)alloc((size_t)NNODES * HEADS * 4);
    float* er1   = (float*)alloc((size_t)NNODES * HEADS * 4);
    float* el2   = (float*)alloc((size_t)NNODES * 4);
    float* er2   = (float*)alloc((size_t)NNODES * 4);
    int* deg     = (int*)alloc((size_t)NNODES * 4);
    int* cursor  = (int*)alloc((size_t)NNODES * 4);
    int* offs    = (int*)alloc((size_t)(NNODES + 1) * 4);
    int* ssorted = (int*)alloc((size_t)NEDGES * 4);

    // --- CSR build (dst is identical for both layers; build once per call) ---
    hipMemsetAsync(deg, 0, (size_t)NNODES * 4, stream);
    hipMemsetAsync(cursor, 0, (size_t)NNODES * 4, stream);
    hist_kernel<<<(NEDGES + 255) / 256, 256, 0, stream>>>(dst, deg);
    scan_kernel<<<1, 1024, 0, stream>>>(deg, offs);
    scatter_kernel<<<(NEDGES + 255) / 256, 256, 0, stream>>>(src, dst, offs, cursor, ssorted);

    // --- Layer 1 ---
    gemm_kernel<<<dim3(256 / 64, (NNODES + 63) / 64), 256, 0, stream>>>(
        x, W1, feat1, NNODES, 256, 256);
    elr1_kernel<<<NNODES, 256, 0, stream>>>(feat1, al1, ar1, el1, er1);
    agg1_kernel<<<NNODES, 256, 0, stream>>>(feat1, el1, er1, offs, ssorted, h1);

    // --- Layer 2 ---
    gemm_kernel<<<dim3(64 / 64, (NNODES + 63) / 64), 256, 0, stream>>>(
        h1, W2, feat2, NNODES, 64, 256);
    elr2_kernel<<<NNODES, 64, 0, stream>>>(feat2, al2, ar2, el2, er2);
    agg2_kernel<<<NNODES, 64, 0, stream>>>(feat2, el2, er2, offs, ssorted, out);
}

// Round 2
// 676.658 us; speedup vs baseline: 1.0203x; 1.0203x over previous
//
#include <hip/hip_runtime.h>
#include <math.h>

#define NNODES 50000
#define NEDGES 800000
#define INDIM 256
#define HID 64
#define HEADS 4
#define OUTDIM 64
#define NEG_SLOPE 0.2f

// ---------------- CSR build ----------------

__global__ __launch_bounds__(256) void hist_kernel(const int* __restrict__ dst,
                                                   int* __restrict__ deg) {
    int i = blockIdx.x * 256 + threadIdx.x;
    if (i < NEDGES) atomicAdd(&deg[dst[i]], 1);
}

__global__ __launch_bounds__(1024) void scan_kernel(const int* __restrict__ deg,
                                                    int* __restrict__ offs) {
    const int n = NNODES;
    int t = threadIdx.x;
    int lane = t & 63, wid = t >> 6;
    const int per = (n + 1023) / 1024;  // 49
    int s0 = t * per;
    int sum = 0;
    for (int i = 0; i < per; ++i) { int idx = s0 + i; if (idx < n) sum += deg[idx]; }
    int v = sum;
    #pragma unroll
    for (int o = 1; o < 64; o <<= 1) { int u = __shfl_up(v, o); if (lane >= o) v += u; }
    __shared__ int wsum[16];
    if (lane == 63) wsum[wid] = v;
    __syncthreads();
    if (t < 16) {
        int wv = wsum[t];
        #pragma unroll
        for (int o = 1; o < 16; o <<= 1) { int u = __shfl_up(wv, o); if (t >= o) wv += u; }
        wsum[t] = wv;  // inclusive scan of wave sums
    }
    __syncthreads();
    int waveoff = (wid == 0) ? 0 : wsum[wid - 1];
    int run = waveoff + v - sum;  // exclusive prefix for this thread's chunk
    for (int i = 0; i < per; ++i) {
        int idx = s0 + i;
        if (idx < n) { offs[idx] = run; run += deg[idx]; }
    }
    if (t == 1023) offs[n] = run;  // total = NEDGES
}

__global__ __launch_bounds__(256) void scatter_kernel(const int* __restrict__ src,
                                                      const int* __restrict__ dst,
                                                      const int* __restrict__ offs,
                                                      int* __restrict__ cursor,
                                                      int* __restrict__ ssorted) {
    int i = blockIdx.x * 256 + threadIdx.x;
    if (i < NEDGES) {
        int d = dst[i];
        int pos = offs[d] + atomicAdd(&cursor[d], 1);
        ssorted[pos] = src[i];
    }
}

// ---------------- fp32 tiled GEMM: C[M,N] = A[M,K] @ B[K,N] ----------------

__global__ __launch_bounds__(256) void gemm_kernel(const float* __restrict__ A,
                                                   const float* __restrict__ B,
                                                   float* __restrict__ C,
                                                   int M, int N, int K) {
    __shared__ float As[16][65];  // [k][m], padded
    __shared__ float Bs[16][64];  // [k][n]
    int t = threadIdx.x;
    int tx = t & 15, ty = t >> 4;
    int m0 = blockIdx.y * 64, n0 = blockIdx.x * 64;
    float acc[4][4] = {};
    for (int k0 = 0; k0 < K; k0 += 16) {
        #pragma unroll
        for (int i = 0; i < 4; ++i) {
            int li = t + i * 256;      // [64][16]: m=li>>4, k=li&15
            int m = li >> 4, k = li & 15;
            int gm = m0 + m;
            As[k][m] = (gm < M) ? A[(size_t)gm * K + k0 + k] : 0.f;
        }
        #pragma unroll
        for (int i = 0; i < 4; ++i) {
            int li = t + i * 256;      // [16][64]: k=li>>6, n=li&63
            int k = li >> 6, nn = li & 63;
            Bs[k][nn] = B[(size_t)(k0 + k) * N + n0 + nn];
        }
        __syncthreads();
        #pragma unroll
        for (int k = 0; k < 16; ++k) {
            float a[4], b[4];
            #pragma unroll
            for (int i = 0; i < 4; ++i) a[i] = As[k][ty * 4 + i];
            #pragma unroll
            for (int j = 0; j < 4; ++j) b[j] = Bs[k][tx * 4 + j];
            #pragma unroll
            for (int i = 0; i < 4; ++i)
                #pragma unroll
                for (int j = 0; j < 4; ++j)
                    acc[i][j] = fmaf(a[i], b[j], acc[i][j]);
        }
        __syncthreads();
    }
    #pragma unroll
    for (int i = 0; i < 4; ++i) {
        int gm = m0 + ty * 4 + i;
        if (gm < M) {
            #pragma unroll
            for (int j = 0; j < 4; ++j)
                C[(size_t)gm * N + n0 + tx * 4 + j] = acc[i][j];
        }
    }
}

// ---------------- attention coefficient dot products ----------------

__global__ __launch_bounds__(256) void elr1_kernel(const float* __restrict__ feat,
                                                   const float* __restrict__ al,
                                                   const float* __restrict__ ar,
                                                   float* __restrict__ el,
                                                   float* __restrict__ er) {
    int n = blockIdx.x;
    int t = threadIdx.x;         // t = h*64 + d
    int h = t >> 6, d = t & 63;
    float f = feat[(size_t)n * 256 + t];
    float a = f * al[t];
    float b = f * ar[t];
    #pragma unroll
    for (int o = 32; o; o >>= 1) { a += __shfl_xor(a, o); b += __shfl_xor(b, o); }
    if (d == 0) { el[n * HEADS + h] = a; er[n * HEADS + h] = b; }
}

__global__ __launch_bounds__(64) void elr2_kernel(const float* __restrict__ feat,
                                                  const float* __restrict__ al,
                                                  const float* __restrict__ ar,
                                                  float* __restrict__ el,
                                                  float* __restrict__ er) {
    int n = blockIdx.x, d = threadIdx.x;
    float f = feat[(size_t)n * 64 + d];
    float a = f * al[d], b = f * ar[d];
    #pragma unroll
    for (int o = 32; o; o >>= 1) { a += __shfl_xor(a, o); b += __shfl_xor(b, o); }
    if (d == 0) { el[n] = a; er[n] = b; }
}

// ---------------- softmax weights (alpha) per edge ----------------
// Layer 1: 4 heads. One wave per node (4 nodes/block). Two passes over the
// node's edges: (1) online (m,s) per head, lane-parallel; (2) write alpha.

__global__ __launch_bounds__(256) void alpha1_kernel(const float4* __restrict__ el,  // [N]
                                                     const float4* __restrict__ er,  // [N]
                                                     const int* __restrict__ offs,
                                                     const int* __restrict__ ssorted,
                                                     float4* __restrict__ alpha) {   // [E]
    int n = blockIdx.x * 4 + (threadIdx.x >> 6);
    int l = threadIdx.x & 63;
    int start = offs[n], end = offs[n + 1];
    if (start == end) return;
    float4 ern = er[n];
    float m0 = -INFINITY, m1 = -INFINITY, m2 = -INFINITY, m3 = -INFINITY;
    float s0 = 0.f, s1 = 0.f, s2 = 0.f, s3 = 0.f;
    for (int base = start; base + l < end; base += 64) {
        int sj = ssorted[base + l];
        float4 ev = el[sj];
        float e0 = ev.x + ern.x; e0 = e0 > 0.f ? e0 : NEG_SLOPE * e0;
        float e1 = ev.y + ern.y; e1 = e1 > 0.f ? e1 : NEG_SLOPE * e1;
        float e2 = ev.z + ern.z; e2 = e2 > 0.f ? e2 : NEG_SLOPE * e2;
        float e3 = ev.w + ern.w; e3 = e3 > 0.f ? e3 : NEG_SLOPE * e3;
        float nm;
        nm = fmaxf(m0, e0); s0 = (m0 == nm ? s0 : s0 * __expf(m0 - nm)) + __expf(e0 - nm); m0 = nm;
        nm = fmaxf(m1, e1); s1 = (m1 == nm ? s1 : s1 * __expf(m1 - nm)) + __expf(e1 - nm); m1 = nm;
        nm = fmaxf(m2, e2); s2 = (m2 == nm ? s2 : s2 * __expf(m2 - nm)) + __expf(e2 - nm); m2 = nm;
        nm = fmaxf(m3, e3); s3 = (m3 == nm ? s3 : s3 * __expf(m3 - nm)) + __expf(e3 - nm); m3 = nm;
    }
    // butterfly combine (m,s) across 64 lanes
    #pragma unroll
    for (int o = 1; o < 64; o <<= 1) {
        float om, os, nm, sa, sb;
        om = __shfl_xor(m0, o); os = __shfl_xor(s0, o); nm = fmaxf(m0, om);
        sa = (m0 == nm) ? s0 : s0 * __expf(m0 - nm); sb = (om == nm) ? os : os * __expf(om - nm);
        m0 = nm; s0 = sa + sb;
        om = __shfl_xor(m1, o); os = __shfl_xor(s1, o); nm = fmaxf(m1, om);
        sa = (m1 == nm) ? s1 : s1 * __expf(m1 - nm); sb = (om == nm) ? os : os * __expf(om - nm);
        m1 = nm; s1 = sa + sb;
        om = __shfl_xor(m2, o); os = __shfl_xor(s2, o); nm = fmaxf(m2, om);
        sa = (m2 == nm) ? s2 : s2 * __expf(m2 - nm); sb = (om == nm) ? os : os * __expf(om - nm);
        m2 = nm; s2 = sa + sb;
        om = __shfl_xor(m3, o); os = __shfl_xor(s3, o); nm = fmaxf(m3, om);
        sa = (m3 == nm) ? s3 : s3 * __expf(m3 - nm); sb = (om == nm) ? os : os * __expf(om - nm);
        m3 = nm; s3 = sa + sb;
    }
    float r0 = 1.f / s0, r1 = 1.f / s1, r2 = 1.f / s2, r3 = 1.f / s3;
    for (int base = start; base + l < end; base += 64) {
        int sj = ssorted[base + l];
        float4 ev = el[sj];
        float e0 = ev.x + ern.x; e0 = e0 > 0.f ? e0 : NEG_SLOPE * e0;
        float e1 = ev.y + ern.y; e1 = e1 > 0.f ? e1 : NEG_SLOPE * e1;
        float e2 = ev.z + ern.z; e2 = e2 > 0.f ? e2 : NEG_SLOPE * e2;
        float e3 = ev.w + ern.w; e3 = e3 > 0.f ? e3 : NEG_SLOPE * e3;
        float4 a;
        a.x = __expf(e0 - m0) * r0;
        a.y = __expf(e1 - m1) * r1;
        a.z = __expf(e2 - m2) * r2;
        a.w = __expf(e3 - m3) * r3;
        alpha[base + l] = a;
    }
}

// Layer 2: single head, scalar el/er.

__global__ __launch_bounds__(256) void alpha2_kernel(const float* __restrict__ el,
                                                     const float* __restrict__ er,
                                                     const int* __restrict__ offs,
                                                     const int* __restrict__ ssorted,
                                                     float* __restrict__ alpha) {
    int n = blockIdx.x * 4 + (threadIdx.x >> 6);
    int l = threadIdx.x & 63;
    int start = offs[n], end = offs[n + 1];
    if (start == end) return;
    float ern = er[n];
    float m = -INFINITY, s = 0.f;
    for (int base = start; base + l < end; base += 64) {
        int sj = ssorted[base + l];
        float e = el[sj] + ern; e = e > 0.f ? e : NEG_SLOPE * e;
        float nm = fmaxf(m, e);
        s = (m == nm ? s : s * __expf(m - nm)) + __expf(e - nm);
        m = nm;
    }
    #pragma unroll
    for (int o = 1; o < 64; o <<= 1) {
        float om = __shfl_xor(m, o), os = __shfl_xor(s, o);
        float nm = fmaxf(m, om);
        float sa = (m == nm) ? s : s * __expf(m - nm);
        float sb = (om == nm) ? os : os * __expf(om - nm);
        m = nm; s = sa + sb;
    }
    float r = 1.f / s;
    for (int base = start; base + l < end; base += 64) {
        int sj = ssorted[base + l];
        float e = el[sj] + ern; e = e > 0.f ? e : NEG_SLOPE * e;
        alpha[base + l] = __expf(e - m) * r;
    }
}

// ---------------- weighted aggregation (SpMM) ----------------
// Layer 1: row = 256 floats = 64 float4. Block = 4 waves; wave g gathers edge
// pos=start+g (stride 4), lane l loads float4 l of the row. 4 edges in flight.
// Cross-wave reduce via LDS, then fused ELU, write by wave 0.

__global__ __launch_bounds__(256) void spmm1_kernel(const float4* __restrict__ feat,  // [N][64]
                                                    const float* __restrict__ alpha,  // [E][4]
                                                    const int* __restrict__ offs,
                                                    const int* __restrict__ ssorted,
                                                    float4* __restrict__ h1) {
    __shared__ float4 red[3][64];
    int n = blockIdx.x;
    int g = threadIdx.x >> 6, l = threadIdx.x & 63;
    int h = l >> 4;  // head of this lane's 4 columns
    int start = offs[n], end = offs[n + 1];
    float4 acc = {0.f, 0.f, 0.f, 0.f};
    for (int pos = start + g; pos < end; pos += 4) {
        int s = ssorted[pos];
        float a = alpha[pos * 4 + h];
        float4 f = feat[(size_t)s * 64 + l];
        acc.x = fmaf(a, f.x, acc.x);
        acc.y = fmaf(a, f.y, acc.y);
        acc.z = fmaf(a, f.z, acc.z);
        acc.w = fmaf(a, f.w, acc.w);
    }
    if (g) red[g - 1][l] = acc;
    __syncthreads();
    if (!g) {
        float4 b0 = red[0][l], b1 = red[1][l], b2 = red[2][l];
        acc.x += b0.x + b1.x + b2.x;
        acc.y += b0.y + b1.y + b2.y;
        acc.z += b0.z + b1.z + b2.z;
        acc.w += b0.w + b1.w + b2.w;
        acc.x = acc.x > 0.f ? acc.x : __expf(acc.x) - 1.f;   // ELU
        acc.y = acc.y > 0.f ? acc.y : __expf(acc.y) - 1.f;
        acc.z = acc.z > 0.f ? acc.z : __expf(acc.z) - 1.f;
        acc.w = acc.w > 0.f ? acc.w : __expf(acc.w) - 1.f;
        h1[(size_t)n * 64 + l] = acc;
    }
}

// Layer 2: row = 64 floats = 16 float4. Block = 4 waves x 4 subgroups of 16
// lanes; 16 edges in flight. shfl_xor(16,32) intra-wave + LDS cross-wave.

__global__ __launch_bounds__(256) void spmm2_kernel(const float4* __restrict__ feat,  // [N][16]
                                                    const float* __restrict__ alpha,  // [E]
                                                    const int* __restrict__ offs,
                                                    const int* __restrict__ ssorted,
                                                    float4* __restrict__ out) {
    __shared__ float4 red[3][16];
    int n = blockIdx.x;
    int g = threadIdx.x >> 6, l = threadIdx.x & 63;
    int sub = l >> 4, li = l & 15;
    int start = offs[n], end = offs[n + 1];
    float4 acc = {0.f, 0.f, 0.f, 0.f};
    for (int pos = start + g * 4 + sub; pos < end; pos += 16) {
        int s = ssorted[pos];
        float a = alpha[pos];
        float4 f = feat[(size_t)s * 16 + li];
        acc.x = fmaf(a, f.x, acc.x);
        acc.y = fmaf(a, f.y, acc.y);
        acc.z = fmaf(a, f.z, acc.z);
        acc.w = fmaf(a, f.w, acc.w);
    }
    #pragma unroll
    for (int o = 16; o < 64; o <<= 1) {
        acc.x += __shfl_xor(acc.x, o);
        acc.y += __shfl_xor(acc.y, o);
        acc.z += __shfl_xor(acc.z, o);
        acc.w += __shfl_xor(acc.w, o);
    }
    if (g && sub == 0) red[g - 1][li] = acc;
    __syncthreads();
    if (!g && sub == 0) {
        float4 b0 = red[0][li], b1 = red[1][li], b2 = red[2][li];
        acc.x += b0.x + b1.x + b2.x;
        acc.y += b0.y + b1.y + b2.y;
        acc.z += b0.z + b1.z + b2.z;
        acc.w += b0.w + b1.w + b2.w;
        out[(size_t)n * 16 + li] = acc;
    }
}

// ---------------- launch ----------------

extern "C" void kernel_launch(void* const* d_in, const int* in_sizes, int n_in,
                              void* d_out, int out_size, void* d_ws, size_t ws_size,
                              hipStream_t stream) {
    const float* x   = (const float*)d_in[0];
    const int*   src = (const int*)d_in[1];
    const int*   dst = (const int*)d_in[2];
    const float* W1  = (const float*)d_in[3];
    const float* al1 = (const float*)d_in[4];
    const float* ar1 = (const float*)d_in[5];
    const float* W2  = (const float*)d_in[6];
    const float* al2 = (const float*)d_in[7];
    const float* ar2 = (const float*)d_in[8];
    float* out = (float*)d_out;

    char* ws = (char*)d_ws;
    size_t off = 0;
    auto alloc = [&](size_t bytes) -> void* {
        void* p = ws + off;
        off += (bytes + 255) & ~(size_t)255;
        return p;
    };
    float* feat1  = (float*)alloc((size_t)NNODES * 256 * 4);   // 51.2 MB
    float* h1     = (float*)alloc((size_t)NNODES * 256 * 4);   // 51.2 MB
    float* feat2  = (float*)alloc((size_t)NNODES * 64 * 4);    // 12.8 MB
    float* el1    = (float*)alloc((size_t)NNODES * HEADS * 4);
    float* er1    = (float*)alloc((size_t)NNODES * HEADS * 4);
    float* el2    = (float*)alloc((size_t)NNODES * 4);
    float* er2    = (float*)alloc((size_t)NNODES * 4);
    float* alpha1 = (float*)alloc((size_t)NEDGES * HEADS * 4); // 12.8 MB
    float* alpha2 = (float*)alloc((size_t)NEDGES * 4);         // 3.2 MB
    int* deg      = (int*)alloc((size_t)NNODES * 4);
    int* cursor   = (int*)alloc((size_t)NNODES * 4);
    int* offs     = (int*)alloc((size_t)(NNODES + 1) * 4);
    int* ssorted  = (int*)alloc((size_t)NEDGES * 4);

    // --- CSR build (dst identical for both layers; build once per call) ---
    hipMemsetAsync(deg, 0, (size_t)NNODES * 4, stream);
    hipMemsetAsync(cursor, 0, (size_t)NNODES * 4, stream);
    hist_kernel<<<(NEDGES + 255) / 256, 256, 0, stream>>>(dst, deg);
    scan_kernel<<<1, 1024, 0, stream>>>(deg, offs);
    scatter_kernel<<<(NEDGES + 255) / 256, 256, 0, stream>>>(src, dst, offs, cursor, ssorted);

    // --- Layer 1 ---
    gemm_kernel<<<dim3(256 / 64, (NNODES + 63) / 64), 256, 0, stream>>>(
        x, W1, feat1, NNODES, 256, 256);
    elr1_kernel<<<NNODES, 256, 0, stream>>>(feat1, al1, ar1, el1, er1);
    alpha1_kernel<<<NNODES / 4, 256, 0, stream>>>(
        (const float4*)el1, (const float4*)er1, offs, ssorted, (float4*)alpha1);
    spmm1_kernel<<<NNODES, 256, 0, stream>>>(
        (const float4*)feat1, alpha1, offs, ssorted, (float4*)h1);

    // --- Layer 2 ---
    gemm_kernel<<<dim3(64 / 64, (NNODES + 63) / 64), 256, 0, stream>>>(
        h1, W2, feat2, NNODES, 64, 256);
    elr2_kernel<<<NNODES, 64, 0, stream>>>(feat2, al2, ar2, el2, er2);
    alpha2_kernel<<<NNODES / 4, 256, 0, stream>>>(el2, er2, offs, ssorted, alpha2);
    spmm2_kernel<<<NNODES, 256, 0, stream>>>(
        (const float4*)feat2, alpha2, offs, ssorted, (float4*)out);
}

// Round 3
// 619.713 us; speedup vs baseline: 1.1140x; 1.0919x over previous
//
#include <hip/hip_runtime.h>
#include <math.h>

#define NNODES 50000
#define NEDGES 800000
#define INDIM 256
#define HID 64
#define HEADS 4
#define OUTDIM 64
#define NEG_SLOPE 0.2f

typedef __attribute__((ext_vector_type(8))) short short8;   // 8 bf16 = 4 VGPRs
typedef __attribute__((ext_vector_type(4))) float f32x4;

__device__ inline unsigned short bf16_rtn(float f) {
    unsigned int u = __float_as_uint(f);
    unsigned int r = u + 0x7fffu + ((u >> 16) & 1u);
    return (unsigned short)(r >> 16);
}
__device__ inline float bf16_to_f32(unsigned short h) {
    return __uint_as_float((unsigned int)h << 16);
}

// ---------------- CSR build ----------------

__global__ __launch_bounds__(256) void hist_kernel(const int* __restrict__ dst,
                                                   int* __restrict__ deg) {
    int i = blockIdx.x * 256 + threadIdx.x;
    if (i < NEDGES) atomicAdd(&deg[dst[i]], 1);
}

__global__ __launch_bounds__(1024) void scan_kernel(const int* __restrict__ deg,
                                                    int* __restrict__ offs) {
    const int n = NNODES;
    int t = threadIdx.x;
    int lane = t & 63, wid = t >> 6;
    const int per = (n + 1023) / 1024;  // 49
    int s0 = t * per;
    int sum = 0;
    for (int i = 0; i < per; ++i) { int idx = s0 + i; if (idx < n) sum += deg[idx]; }
    int v = sum;
    #pragma unroll
    for (int o = 1; o < 64; o <<= 1) { int u = __shfl_up(v, o); if (lane >= o) v += u; }
    __shared__ int wsum[16];
    if (lane == 63) wsum[wid] = v;
    __syncthreads();
    if (t < 16) {
        int wv = wsum[t];
        #pragma unroll
        for (int o = 1; o < 16; o <<= 1) { int u = __shfl_up(wv, o); if (t >= o) wv += u; }
        wsum[t] = wv;
    }
    __syncthreads();
    int waveoff = (wid == 0) ? 0 : wsum[wid - 1];
    int run = waveoff + v - sum;
    for (int i = 0; i < per; ++i) {
        int idx = s0 + i;
        if (idx < n) { offs[idx] = run; run += deg[idx]; }
    }
    if (t == 1023) offs[n] = run;
}

__global__ __launch_bounds__(256) void scatter_kernel(const int* __restrict__ src,
                                                      const int* __restrict__ dst,
                                                      const int* __restrict__ offs,
                                                      int* __restrict__ cursor,
                                                      int* __restrict__ ssorted) {
    int i = blockIdx.x * 256 + threadIdx.x;
    if (i < NEDGES) {
        int d = dst[i];
        int pos = offs[d] + atomicAdd(&cursor[d], 1);
        ssorted[pos] = src[i];
    }
}

// ---------------- split-bf16 conversions ----------------

__global__ __launch_bounds__(256) void convert_x_kernel(const float4* __restrict__ x,
                                                        unsigned short* __restrict__ hi,
                                                        unsigned short* __restrict__ lo,
                                                        int n4) {
    int i = blockIdx.x * 256 + threadIdx.x;
    if (i >= n4) return;
    float4 v = x[i];
    unsigned short h0 = bf16_rtn(v.x), h1 = bf16_rtn(v.y), h2 = bf16_rtn(v.z), h3 = bf16_rtn(v.w);
    ushort4 hv = make_ushort4(h0, h1, h2, h3);
    ushort4 lv = make_ushort4(bf16_rtn(v.x - bf16_to_f32(h0)),
                              bf16_rtn(v.y - bf16_to_f32(h1)),
                              bf16_rtn(v.z - bf16_to_f32(h2)),
                              bf16_rtn(v.w - bf16_to_f32(h3)));
    *(ushort4*)&hi[i * 4] = hv;
    *(ushort4*)&lo[i * 4] = lv;
}

// W [K][N] row-major -> transposed split Wt_hi/Wt_lo [N][K]
__global__ __launch_bounds__(256) void convert_wt_kernel(const float* __restrict__ W,
                                                         unsigned short* __restrict__ hi,
                                                         unsigned short* __restrict__ lo,
                                                         int K, int N) {
    int idx = blockIdx.x * 256 + threadIdx.x;
    if (idx >= K * N) return;
    int k = idx / N, n = idx - k * N;
    float v = W[idx];
    unsigned short h = bf16_rtn(v);
    hi[n * K + k] = h;
    lo[n * K + k] = bf16_rtn(v - bf16_to_f32(h));
}

// ---------------- split-bf16 MFMA GEMM ----------------
// C[M,N] = (Ahi+Alo) @ (Bhi+Blo)^T_t  with A row-major [M,K] (bf16 hi/lo),
// Bt row-major [N,K] (pre-transposed). BM=128, BK=32, 4 waves in 2x2 grid,
// per-wave 4 x NT tiles of 16x16 (NT = BN/32). 3 MFMA products (hh, hl, lh).
// LDS rows padded to 40 ushorts (80B stride -> only 2-way conflicts = free).

template <int BN>
__global__ __launch_bounds__(256) void gemm_mfma_kernel(
        const unsigned short* __restrict__ Ahi, const unsigned short* __restrict__ Alo,
        const unsigned short* __restrict__ Bthi, const unsigned short* __restrict__ Btlo,
        float* __restrict__ C, int M, int N, int K) {
    constexpr int NT = BN / 32;       // n-tiles per wave
    constexpr int PB = BN / 64;       // B staging passes
    __shared__ unsigned short As_hi[128 * 40], As_lo[128 * 40];
    __shared__ unsigned short Bs_hi[BN * 40], Bs_lo[BN * 40];
    int t = threadIdx.x;
    int lane = t & 63, w = t >> 6;
    int wm = w >> 1, wn = w & 1;
    int lr = lane & 15, quad = lane >> 4;
    int m0 = blockIdx.y * 128, n0 = blockIdx.x * BN;

    f32x4 acc[4][NT];
    #pragma unroll
    for (int i = 0; i < 4; ++i)
        #pragma unroll
        for (int j = 0; j < NT; ++j) acc[i][j] = (f32x4){0.f, 0.f, 0.f, 0.f};

    int srow = t >> 2, schunk = t & 3;  // staging: row/16B-chunk per thread

    for (int kk = 0; kk < K; kk += 32) {
        uint4 rah[2], ral[2], rbh[PB], rbl[PB];
        #pragma unroll
        for (int p = 0; p < 2; ++p) {
            int row = srow + p * 64;
            int gr = m0 + row;
            if (gr < M) {
                size_t off = (size_t)gr * K + kk + schunk * 8;
                rah[p] = *(const uint4*)(Ahi + off);
                ral[p] = *(const uint4*)(Alo + off);
            } else {
                rah[p] = make_uint4(0, 0, 0, 0);
                ral[p] = make_uint4(0, 0, 0, 0);
            }
        }
        #pragma unroll
        for (int p = 0; p < PB; ++p) {
            int row = srow + p * 64;
            size_t off = (size_t)(n0 + row) * K + kk + schunk * 8;
            rbh[p] = *(const uint4*)(Bthi + off);
            rbl[p] = *(const uint4*)(Btlo + off);
        }
        __syncthreads();
        #pragma unroll
        for (int p = 0; p < 2; ++p) {
            int row = srow + p * 64;
            *(uint4*)(As_hi + row * 40 + schunk * 8) = rah[p];
            *(uint4*)(As_lo + row * 40 + schunk * 8) = ral[p];
        }
        #pragma unroll
        for (int p = 0; p < PB; ++p) {
            int row = srow + p * 64;
            *(uint4*)(Bs_hi + row * 40 + schunk * 8) = rbh[p];
            *(uint4*)(Bs_lo + row * 40 + schunk * 8) = rbl[p];
        }
        __syncthreads();

        short8 ah[4], al[4], bh[NT], bl[NT];
        #pragma unroll
        for (int i = 0; i < 4; ++i) {
            int r = wm * 64 + i * 16 + lr;
            ah[i] = *(const short8*)(As_hi + r * 40 + quad * 8);
            al[i] = *(const short8*)(As_lo + r * 40 + quad * 8);
        }
        #pragma unroll
        for (int j = 0; j < NT; ++j) {
            int r = wn * NT * 16 + j * 16 + lr;
            bh[j] = *(const short8*)(Bs_hi + r * 40 + quad * 8);
            bl[j] = *(const short8*)(Bs_lo + r * 40 + quad * 8);
        }
        #pragma unroll
        for (int i = 0; i < 4; ++i)
            #pragma unroll
            for (int j = 0; j < NT; ++j) {
                acc[i][j] = __builtin_amdgcn_mfma_f32_16x16x32_bf16(ah[i], bh[j], acc[i][j], 0, 0, 0);
                acc[i][j] = __builtin_amdgcn_mfma_f32_16x16x32_bf16(ah[i], bl[j], acc[i][j], 0, 0, 0);
                acc[i][j] = __builtin_amdgcn_mfma_f32_16x16x32_bf16(al[i], bh[j], acc[i][j], 0, 0, 0);
            }
        __syncthreads();
    }
    #pragma unroll
    for (int i = 0; i < 4; ++i) {
        #pragma unroll
        for (int r = 0; r < 4; ++r) {
            int row = m0 + wm * 64 + i * 16 + quad * 4 + r;
            if (row < M) {
                #pragma unroll
                for (int j = 0; j < NT; ++j)
                    C[(size_t)row * N + n0 + wn * NT * 16 + j * 16 + lr] = acc[i][j][r];
            }
        }
    }
}

// ---------------- attention coefficient dot products ----------------

__global__ __launch_bounds__(256) void elr1_kernel(const float* __restrict__ feat,
                                                   const float* __restrict__ al,
                                                   const float* __restrict__ ar,
                                                   float* __restrict__ el,
                                                   float* __restrict__ er) {
    int n = blockIdx.x;
    int t = threadIdx.x;         // t = h*64 + d
    int h = t >> 6, d = t & 63;
    float f = feat[(size_t)n * 256 + t];
    float a = f * al[t];
    float b = f * ar[t];
    #pragma unroll
    for (int o = 32; o; o >>= 1) { a += __shfl_xor(a, o); b += __shfl_xor(b, o); }
    if (d == 0) { el[n * HEADS + h] = a; er[n * HEADS + h] = b; }
}

__global__ __launch_bounds__(64) void elr2_kernel(const float* __restrict__ feat,
                                                  const float* __restrict__ al,
                                                  const float* __restrict__ ar,
                                                  float* __restrict__ el,
                                                  float* __restrict__ er) {
    int n = blockIdx.x, d = threadIdx.x;
    float f = feat[(size_t)n * 64 + d];
    float a = f * al[d], b = f * ar[d];
    #pragma unroll
    for (int o = 32; o; o >>= 1) { a += __shfl_xor(a, o); b += __shfl_xor(b, o); }
    if (d == 0) { el[n] = a; er[n] = b; }
}

// ---------------- softmax weights (alpha) per edge ----------------

__global__ __launch_bounds__(256) void alpha1_kernel(const float4* __restrict__ el,
                                                     const float4* __restrict__ er,
                                                     const int* __restrict__ offs,
                                                     const int* __restrict__ ssorted,
                                                     float4* __restrict__ alpha) {
    int n = blockIdx.x * 4 + (threadIdx.x >> 6);
    int l = threadIdx.x & 63;
    int start = offs[n], end = offs[n + 1];
    if (start == end) return;
    float4 ern = er[n];
    float m0 = -INFINITY, m1 = -INFINITY, m2 = -INFINITY, m3 = -INFINITY;
    float s0 = 0.f, s1 = 0.f, s2 = 0.f, s3 = 0.f;
    for (int base = start; base + l < end; base += 64) {
        int sj = ssorted[base + l];
        float4 ev = el[sj];
        float e0 = ev.x + ern.x; e0 = e0 > 0.f ? e0 : NEG_SLOPE * e0;
        float e1 = ev.y + ern.y; e1 = e1 > 0.f ? e1 : NEG_SLOPE * e1;
        float e2 = ev.z + ern.z; e2 = e2 > 0.f ? e2 : NEG_SLOPE * e2;
        float e3 = ev.w + ern.w; e3 = e3 > 0.f ? e3 : NEG_SLOPE * e3;
        float nm;
        nm = fmaxf(m0, e0); s0 = (m0 == nm ? s0 : s0 * __expf(m0 - nm)) + __expf(e0 - nm); m0 = nm;
        nm = fmaxf(m1, e1); s1 = (m1 == nm ? s1 : s1 * __expf(m1 - nm)) + __expf(e1 - nm); m1 = nm;
        nm = fmaxf(m2, e2); s2 = (m2 == nm ? s2 : s2 * __expf(m2 - nm)) + __expf(e2 - nm); m2 = nm;
        nm = fmaxf(m3, e3); s3 = (m3 == nm ? s3 : s3 * __expf(m3 - nm)) + __expf(e3 - nm); m3 = nm;
    }
    #pragma unroll
    for (int o = 1; o < 64; o <<= 1) {
        float om, os, nm, sa, sb;
        om = __shfl_xor(m0, o); os = __shfl_xor(s0, o); nm = fmaxf(m0, om);
        sa = (m0 == nm) ? s0 : s0 * __expf(m0 - nm); sb = (om == nm) ? os : os * __expf(om - nm);
        m0 = nm; s0 = sa + sb;
        om = __shfl_xor(m1, o); os = __shfl_xor(s1, o); nm = fmaxf(m1, om);
        sa = (m1 == nm) ? s1 : s1 * __expf(m1 - nm); sb = (om == nm) ? os : os * __expf(om - nm);
        m1 = nm; s1 = sa + sb;
        om = __shfl_xor(m2, o); os = __shfl_xor(s2, o); nm = fmaxf(m2, om);
        sa = (m2 == nm) ? s2 : s2 * __expf(m2 - nm); sb = (om == nm) ? os : os * __expf(om - nm);
        m2 = nm; s2 = sa + sb;
        om = __shfl_xor(m3, o); os = __shfl_xor(s3, o); nm = fmaxf(m3, om);
        sa = (m3 == nm) ? s3 : s3 * __expf(m3 - nm); sb = (om == nm) ? os : os * __expf(om - nm);
        m3 = nm; s3 = sa + sb;
    }
    float r0 = 1.f / s0, r1 = 1.f / s1, r2 = 1.f / s2, r3 = 1.f / s3;
    for (int base = start; base + l < end; base += 64) {
        int sj = ssorted[base + l];
        float4 ev = el[sj];
        float e0 = ev.x + ern.x; e0 = e0 > 0.f ? e0 : NEG_SLOPE * e0;
        float e1 = ev.y + ern.y; e1 = e1 > 0.f ? e1 : NEG_SLOPE * e1;
        float e2 = ev.z + ern.z; e2 = e2 > 0.f ? e2 : NEG_SLOPE * e2;
        float e3 = ev.w + ern.w; e3 = e3 > 0.f ? e3 : NEG_SLOPE * e3;
        float4 a;
        a.x = __expf(e0 - m0) * r0;
        a.y = __expf(e1 - m1) * r1;
        a.z = __expf(e2 - m2) * r2;
        a.w = __expf(e3 - m3) * r3;
        alpha[base + l] = a;
    }
}

__global__ __launch_bounds__(256) void alpha2_kernel(const float* __restrict__ el,
                                                     const float* __restrict__ er,
                                                     const int* __restrict__ offs,
                                                     const int* __restrict__ ssorted,
                                                     float* __restrict__ alpha) {
    int n = blockIdx.x * 4 + (threadIdx.x >> 6);
    int l = threadIdx.x & 63;
    int start = offs[n], end = offs[n + 1];
    if (start == end) return;
    float ern = er[n];
    float m = -INFINITY, s = 0.f;
    for (int base = start; base + l < end; base += 64) {
        int sj = ssorted[base + l];
        float e = el[sj] + ern; e = e > 0.f ? e : NEG_SLOPE * e;
        float nm = fmaxf(m, e);
        s = (m == nm ? s : s * __expf(m - nm)) + __expf(e - nm);
        m = nm;
    }
    #pragma unroll
    for (int o = 1; o < 64; o <<= 1) {
        float om = __shfl_xor(m, o), os = __shfl_xor(s, o);
        float nm = fmaxf(m, om);
        float sa = (m == nm) ? s : s * __expf(m - nm);
        float sb = (om == nm) ? os : os * __expf(om - nm);
        m = nm; s = sa + sb;
    }
    float r = 1.f / s;
    for (int base = start; base + l < end; base += 64) {
        int sj = ssorted[base + l];
        float e = el[sj] + ern; e = e > 0.f ? e : NEG_SLOPE * e;
        alpha[base + l] = __expf(e - m) * r;
    }
}

// ---------------- weighted aggregation (SpMM) ----------------
// Layer 1: writes h1 directly as split-bf16 hi/lo (consumed by GEMM2).

__global__ __launch_bounds__(256) void spmm1_kernel(const float4* __restrict__ feat,
                                                    const float* __restrict__ alpha,
                                                    const int* __restrict__ offs,
                                                    const int* __restrict__ ssorted,
                                                    unsigned short* __restrict__ h1hi,
                                                    unsigned short* __restrict__ h1lo) {
    __shared__ float4 red[3][64];
    int n = blockIdx.x;
    int g = threadIdx.x >> 6, l = threadIdx.x & 63;
    int h = l >> 4;
    int start = offs[n], end = offs[n + 1];
    float4 acc = {0.f, 0.f, 0.f, 0.f};
    for (int pos = start + g; pos < end; pos += 4) {
        int s = ssorted[pos];
        float a = alpha[pos * 4 + h];
        float4 f = feat[(size_t)s * 64 + l];
        acc.x = fmaf(a, f.x, acc.x);
        acc.y = fmaf(a, f.y, acc.y);
        acc.z = fmaf(a, f.z, acc.z);
        acc.w = fmaf(a, f.w, acc.w);
    }
    if (g) red[g - 1][l] = acc;
    __syncthreads();
    if (!g) {
        float4 b0 = red[0][l], b1 = red[1][l], b2 = red[2][l];
        acc.x += b0.x + b1.x + b2.x;
        acc.y += b0.y + b1.y + b2.y;
        acc.z += b0.z + b1.z + b2.z;
        acc.w += b0.w + b1.w + b2.w;
        acc.x = acc.x > 0.f ? acc.x : __expf(acc.x) - 1.f;   // ELU
        acc.y = acc.y > 0.f ? acc.y : __expf(acc.y) - 1.f;
        acc.z = acc.z > 0.f ? acc.z : __expf(acc.z) - 1.f;
        acc.w = acc.w > 0.f ? acc.w : __expf(acc.w) - 1.f;
        unsigned short h0 = bf16_rtn(acc.x), h1 = bf16_rtn(acc.y),
                       h2 = bf16_rtn(acc.z), h3 = bf16_rtn(acc.w);
        ushort4 hv = make_ushort4(h0, h1, h2, h3);
        ushort4 lv = make_ushort4(bf16_rtn(acc.x - bf16_to_f32(h0)),
                                  bf16_rtn(acc.y - bf16_to_f32(h1)),
                                  bf16_rtn(acc.z - bf16_to_f32(h2)),
                                  bf16_rtn(acc.w - bf16_to_f32(h3)));
        *(ushort4*)&h1hi[(size_t)n * 256 + l * 4] = hv;
        *(ushort4*)&h1lo[(size_t)n * 256 + l * 4] = lv;
    }
}

__global__ __launch_bounds__(256) void spmm2_kernel(const float4* __restrict__ feat,
                                                    const float* __restrict__ alpha,
                                                    const int* __restrict__ offs,
                                                    const int* __restrict__ ssorted,
                                                    float4* __restrict__ out) {
    __shared__ float4 red[3][16];
    int n = blockIdx.x;
    int g = threadIdx.x >> 6, l = threadIdx.x & 63;
    int sub = l >> 4, li = l & 15;
    int start = offs[n], end = offs[n + 1];
    float4 acc = {0.f, 0.f, 0.f, 0.f};
    for (int pos = start + g * 4 + sub; pos < end; pos += 16) {
        int s = ssorted[pos];
        float a = alpha[pos];
        float4 f = feat[(size_t)s * 16 + li];
        acc.x = fmaf(a, f.x, acc.x);
        acc.y = fmaf(a, f.y, acc.y);
        acc.z = fmaf(a, f.z, acc.z);
        acc.w = fmaf(a, f.w, acc.w);
    }
    #pragma unroll
    for (int o = 16; o < 64; o <<= 1) {
        acc.x += __shfl_xor(acc.x, o);
        acc.y += __shfl_xor(acc.y, o);
        acc.z += __shfl_xor(acc.z, o);
        acc.w += __shfl_xor(acc.w, o);
    }
    if (g && sub == 0) red[g - 1][li] = acc;
    __syncthreads();
    if (!g && sub == 0) {
        float4 b0 = red[0][li], b1 = red[1][li], b2 = red[2][li];
        acc.x += b0.x + b1.x + b2.x;
        acc.y += b0.y + b1.y + b2.y;
        acc.z += b0.z + b1.z + b2.z;
        acc.w += b0.w + b1.w + b2.w;
        out[(size_t)n * 16 + li] = acc;
    }
}

// ---------------- launch ----------------

extern "C" void kernel_launch(void* const* d_in, const int* in_sizes, int n_in,
                              void* d_out, int out_size, void* d_ws, size_t ws_size,
                              hipStream_t stream) {
    const float* x   = (const float*)d_in[0];
    const int*   src = (const int*)d_in[1];
    const int*   dst = (const int*)d_in[2];
    const float* W1  = (const float*)d_in[3];
    const float* al1 = (const float*)d_in[4];
    const float* ar1 = (const float*)d_in[5];
    const float* W2  = (const float*)d_in[6];
    const float* al2 = (const float*)d_in[7];
    const float* ar2 = (const float*)d_in[8];
    float* out = (float*)d_out;

    char* ws = (char*)d_ws;
    size_t off = 0;
    auto alloc = [&](size_t bytes) -> void* {
        void* p = ws + off;
        off += (bytes + 255) & ~(size_t)255;
        return p;
    };
    float* feat1  = (float*)alloc((size_t)NNODES * 256 * 4);        // 51.2 MB
    unsigned short* xhi = (unsigned short*)alloc((size_t)NNODES * 256 * 2);  // 25.6 MB
    unsigned short* xlo = (unsigned short*)alloc((size_t)NNODES * 256 * 2);  // 25.6 MB
    unsigned short* W1hi = (unsigned short*)alloc((size_t)256 * 256 * 2);
    unsigned short* W1lo = (unsigned short*)alloc((size_t)256 * 256 * 2);
    unsigned short* W2hi = (unsigned short*)alloc((size_t)64 * 256 * 2);
    unsigned short* W2lo = (unsigned short*)alloc((size_t)64 * 256 * 2);
    float* el1    = (float*)alloc((size_t)NNODES * HEADS * 4);
    float* er1    = (float*)alloc((size_t)NNODES * HEADS * 4);
    float* el2    = (float*)alloc((size_t)NNODES * 4);
    float* er2    = (float*)alloc((size_t)NNODES * 4);
    float* alpha1 = (float*)alloc((size_t)NEDGES * HEADS * 4);      // 12.8 MB
    float* alpha2 = (float*)alloc((size_t)NEDGES * 4);              // 3.2 MB
    int* deg      = (int*)alloc((size_t)NNODES * 4);
    int* cursor   = (int*)alloc((size_t)NNODES * 4);
    int* offs     = (int*)alloc((size_t)(NNODES + 1) * 4);
    int* ssorted  = (int*)alloc((size_t)NEDGES * 4);
    // aliases: x dead after gemm1 -> h1 hi/lo reuse its space;
    // feat1 dead after spmm1 -> feat2 reuses it.
    unsigned short* h1hi = xhi;
    unsigned short* h1lo = xlo;
    float* feat2 = feat1;

    // --- CSR build ---
    hipMemsetAsync(deg, 0, (size_t)NNODES * 4, stream);
    hipMemsetAsync(cursor, 0, (size_t)NNODES * 4, stream);
    hist_kernel<<<(NEDGES + 255) / 256, 256, 0, stream>>>(dst, deg);
    scan_kernel<<<1, 1024, 0, stream>>>(deg, offs);
    scatter_kernel<<<(NEDGES + 255) / 256, 256, 0, stream>>>(src, dst, offs, cursor, ssorted);

    // --- conversions ---
    convert_x_kernel<<<(NNODES * 256 / 4 + 255) / 256, 256, 0, stream>>>(
        (const float4*)x, xhi, xlo, NNODES * 256 / 4);
    convert_wt_kernel<<<(256 * 256 + 255) / 256, 256, 0, stream>>>(W1, W1hi, W1lo, 256, 256);
    convert_wt_kernel<<<(256 * 64 + 255) / 256, 256, 0, stream>>>(W2, W2hi, W2lo, 256, 64);

    // --- Layer 1 ---
    gemm_mfma_kernel<128><<<dim3(256 / 128, (NNODES + 127) / 128), 256, 0, stream>>>(
        xhi, xlo, W1hi, W1lo, feat1, NNODES, 256, 256);
    elr1_kernel<<<NNODES, 256, 0, stream>>>(feat1, al1, ar1, el1, er1);
    alpha1_kernel<<<NNODES / 4, 256, 0, stream>>>(
        (const float4*)el1, (const float4*)er1, offs, ssorted, (float4*)alpha1);
    spmm1_kernel<<<NNODES, 256, 0, stream>>>(
        (const float4*)feat1, alpha1, offs, ssorted, h1hi, h1lo);

    // --- Layer 2 ---
    gemm_mfma_kernel<64><<<dim3(64 / 64, (NNODES + 127) / 128), 256, 0, stream>>>(
        h1hi, h1lo, W2hi, W2lo, feat2, NNODES, 64, 256);
    elr2_kernel<<<NNODES, 64, 0, stream>>>(feat2, al2, ar2, el2, er2);
    alpha2_kernel<<<NNODES / 4, 256, 0, stream>>>(el2, er2, offs, ssorted, alpha2);
    spmm2_kernel<<<NNODES, 256, 0, stream>>>(
        (const float4*)feat2, alpha2, offs, ssorted, (float4*)out);
}

// Round 4
// 586.904 us; speedup vs baseline: 1.1763x; 1.0559x over previous
//
#include <hip/hip_runtime.h>
#include <math.h>

#define NNODES 50000
#define NEDGES 800000
#define INDIM 256
#define HID 64
#define HEADS 4
#define OUTDIM 64
#define NEG_SLOPE 0.2f

typedef __attribute__((ext_vector_type(8))) short short8;   // 8 bf16 = 4 VGPRs
typedef __attribute__((ext_vector_type(8))) unsigned short ushort8;
typedef __attribute__((ext_vector_type(4))) float f32x4;

__device__ inline unsigned short bf16_rtn(float f) {
    unsigned int u = __float_as_uint(f);
    unsigned int r = u + 0x7fffu + ((u >> 16) & 1u);
    return (unsigned short)(r >> 16);
}
__device__ inline float bf16_to_f32(unsigned short h) {
    return __uint_as_float((unsigned int)h << 16);
}

// ---------------- CSR build ----------------

__global__ __launch_bounds__(256) void hist_kernel(const int* __restrict__ dst,
                                                   int* __restrict__ deg) {
    int i = blockIdx.x * 256 + threadIdx.x;
    if (i < NEDGES) atomicAdd(&deg[dst[i]], 1);
}

__global__ __launch_bounds__(1024) void scan_kernel(const int* __restrict__ deg,
                                                    int* __restrict__ offs) {
    const int n = NNODES;
    int t = threadIdx.x;
    int lane = t & 63, wid = t >> 6;
    const int per = (n + 1023) / 1024;  // 49
    int s0 = t * per;
    int sum = 0;
    for (int i = 0; i < per; ++i) { int idx = s0 + i; if (idx < n) sum += deg[idx]; }
    int v = sum;
    #pragma unroll
    for (int o = 1; o < 64; o <<= 1) { int u = __shfl_up(v, o); if (lane >= o) v += u; }
    __shared__ int wsum[16];
    if (lane == 63) wsum[wid] = v;
    __syncthreads();
    if (t < 16) {
        int wv = wsum[t];
        #pragma unroll
        for (int o = 1; o < 16; o <<= 1) { int u = __shfl_up(wv, o); if (t >= o) wv += u; }
        wsum[t] = wv;
    }
    __syncthreads();
    int waveoff = (wid == 0) ? 0 : wsum[wid - 1];
    int run = waveoff + v - sum;
    for (int i = 0; i < per; ++i) {
        int idx = s0 + i;
        if (idx < n) { offs[idx] = run; run += deg[idx]; }
    }
    if (t == 1023) offs[n] = run;
}

__global__ __launch_bounds__(256) void scatter_kernel(const int* __restrict__ src,
                                                      const int* __restrict__ dst,
                                                      const int* __restrict__ offs,
                                                      int* __restrict__ cursor,
                                                      int* __restrict__ ssorted) {
    int i = blockIdx.x * 256 + threadIdx.x;
    if (i < NEDGES) {
        int d = dst[i];
        int pos = offs[d] + atomicAdd(&cursor[d], 1);
        ssorted[pos] = src[i];
    }
}

// ---------------- weight transpose+split ----------------
// W [K][N] row-major -> transposed split Wt_hi/Wt_lo [N][K]

__global__ __launch_bounds__(256) void convert_wt_kernel(const float* __restrict__ W,
                                                         unsigned short* __restrict__ hi,
                                                         unsigned short* __restrict__ lo,
                                                         int K, int N) {
    int idx = blockIdx.x * 256 + threadIdx.x;
    if (idx >= K * N) return;
    int k = idx / N, n = idx - k * N;
    float v = W[idx];
    unsigned short h = bf16_rtn(v);
    hi[n * K + k] = h;
    lo[n * K + k] = bf16_rtn(v - bf16_to_f32(h));
}

// ---------------- split-bf16 MFMA GEMM ----------------
// C[M,N] = A @ Bt^T with Bt [N][K] pre-split bf16. A either fp32 [M,K]
// (SPLITA=false, split inline during staging) or pre-split hi/lo bf16.
// BM=128, BK=32, 4 waves 2x2, 3 MFMA products (hh, hl, lh).
// ELR (BN=128 only): each wave's 64 cols = one head -> fused el/er epilogue.

template <int BN, bool SPLITA, bool ELR>
__global__ __launch_bounds__(256) void gemm_mfma_kernel(
        const float* __restrict__ Af,
        const unsigned short* __restrict__ Ahi, const unsigned short* __restrict__ Alo,
        const unsigned short* __restrict__ Bthi, const unsigned short* __restrict__ Btlo,
        float* __restrict__ C,
        const float* __restrict__ al, const float* __restrict__ ar,
        float* __restrict__ el, float* __restrict__ er,
        int M, int N, int K) {
    constexpr int NT = BN / 32;       // n-tiles per wave
    constexpr int PB = BN / 64;       // B staging passes
    __shared__ unsigned short As_hi[128 * 40], As_lo[128 * 40];
    __shared__ unsigned short Bs_hi[BN * 40], Bs_lo[BN * 40];
    int t = threadIdx.x;
    int lane = t & 63, w = t >> 6;
    int wm = w >> 1, wn = w & 1;
    int lr = lane & 15, quad = lane >> 4;
    int m0 = blockIdx.y * 128, n0 = blockIdx.x * BN;

    f32x4 acc[4][NT];
    #pragma unroll
    for (int i = 0; i < 4; ++i)
        #pragma unroll
        for (int j = 0; j < NT; ++j) acc[i][j] = (f32x4){0.f, 0.f, 0.f, 0.f};

    int srow = t >> 2, schunk = t & 3;  // staging: row / 8-elem chunk

    for (int kk = 0; kk < K; kk += 32) {
        uint4 rah[2], ral[2], rbh[PB], rbl[PB];
        float4 fa[2][2];
        #pragma unroll
        for (int p = 0; p < 2; ++p) {
            int row = srow + p * 64;
            int gr = m0 + row;
            if (SPLITA) {
                if (gr < M) {
                    size_t off = (size_t)gr * K + kk + schunk * 8;
                    rah[p] = *(const uint4*)(Ahi + off);
                    ral[p] = *(const uint4*)(Alo + off);
                } else {
                    rah[p] = make_uint4(0, 0, 0, 0);
                    ral[p] = make_uint4(0, 0, 0, 0);
                }
            } else {
                if (gr < M) {
                    size_t off = (size_t)gr * K + kk + schunk * 8;
                    fa[p][0] = *(const float4*)(Af + off);
                    fa[p][1] = *(const float4*)(Af + off + 4);
                } else {
                    fa[p][0] = make_float4(0.f, 0.f, 0.f, 0.f);
                    fa[p][1] = make_float4(0.f, 0.f, 0.f, 0.f);
                }
            }
        }
        #pragma unroll
        for (int p = 0; p < PB; ++p) {
            int row = srow + p * 64;
            size_t off = (size_t)(n0 + row) * K + kk + schunk * 8;
            rbh[p] = *(const uint4*)(Bthi + off);
            rbl[p] = *(const uint4*)(Btlo + off);
        }
        __syncthreads();
        #pragma unroll
        for (int p = 0; p < 2; ++p) {
            int row = srow + p * 64;
            if (SPLITA) {
                *(uint4*)(As_hi + row * 40 + schunk * 8) = rah[p];
                *(uint4*)(As_lo + row * 40 + schunk * 8) = ral[p];
            } else {
                float v[8] = {fa[p][0].x, fa[p][0].y, fa[p][0].z, fa[p][0].w,
                              fa[p][1].x, fa[p][1].y, fa[p][1].z, fa[p][1].w};
                ushort8 hv, lv;
                #pragma unroll
                for (int e = 0; e < 8; ++e) {
                    unsigned short h = bf16_rtn(v[e]);
                    hv[e] = (short)h;
                    lv[e] = (short)bf16_rtn(v[e] - bf16_to_f32(h));
                }
                *(ushort8*)(As_hi + row * 40 + schunk * 8) = hv;
                *(ushort8*)(As_lo + row * 40 + schunk * 8) = lv;
            }
        }
        #pragma unroll
        for (int p = 0; p < PB; ++p) {
            int row = srow + p * 64;
            *(uint4*)(Bs_hi + row * 40 + schunk * 8) = rbh[p];
            *(uint4*)(Bs_lo + row * 40 + schunk * 8) = rbl[p];
        }
        __syncthreads();

        short8 ah[4], alo[4], bh[NT], blo[NT];
        #pragma unroll
        for (int i = 0; i < 4; ++i) {
            int r = wm * 64 + i * 16 + lr;
            ah[i]  = *(const short8*)(As_hi + r * 40 + quad * 8);
            alo[i] = *(const short8*)(As_lo + r * 40 + quad * 8);
        }
        #pragma unroll
        for (int j = 0; j < NT; ++j) {
            int r = wn * NT * 16 + j * 16 + lr;
            bh[j]  = *(const short8*)(Bs_hi + r * 40 + quad * 8);
            blo[j] = *(const short8*)(Bs_lo + r * 40 + quad * 8);
        }
        #pragma unroll
        for (int i = 0; i < 4; ++i)
            #pragma unroll
            for (int j = 0; j < NT; ++j) {
                acc[i][j] = __builtin_amdgcn_mfma_f32_16x16x32_bf16(ah[i], bh[j], acc[i][j], 0, 0, 0);
                acc[i][j] = __builtin_amdgcn_mfma_f32_16x16x32_bf16(ah[i], blo[j], acc[i][j], 0, 0, 0);
                acc[i][j] = __builtin_amdgcn_mfma_f32_16x16x32_bf16(alo[i], bh[j], acc[i][j], 0, 0, 0);
            }
        __syncthreads();
    }
    #pragma unroll
    for (int i = 0; i < 4; ++i) {
        #pragma unroll
        for (int r = 0; r < 4; ++r) {
            int row = m0 + wm * 64 + i * 16 + quad * 4 + r;
            if (row < M) {
                #pragma unroll
                for (int j = 0; j < NT; ++j)
                    C[(size_t)row * N + n0 + wn * NT * 16 + j * 16 + lr] = acc[i][j][r];
            }
        }
    }
    if (ELR) {
        // wave (wm,wn) covers head h = n0/64 + wn, rows [m0+wm*64, +64)
        int h = n0 / 64 + wn;
        float alh[NT], arh[NT];
        #pragma unroll
        for (int j = 0; j < NT; ++j) {
            alh[j] = al[h * 64 + j * 16 + lr];
            arh[j] = ar[h * 64 + j * 16 + lr];
        }
        #pragma unroll
        for (int i = 0; i < 4; ++i) {
            #pragma unroll
            for (int r = 0; r < 4; ++r) {
                float pel = 0.f, per = 0.f;
                #pragma unroll
                for (int j = 0; j < NT; ++j) {
                    pel = fmaf(acc[i][j][r], alh[j], pel);
                    per = fmaf(acc[i][j][r], arh[j], per);
                }
                #pragma unroll
                for (int o = 1; o < 16; o <<= 1) {
                    pel += __shfl_xor(pel, o);
                    per += __shfl_xor(per, o);
                }
                if (lr == 0) {
                    int row = m0 + wm * 64 + i * 16 + quad * 4 + r;
                    if (row < M) {
                        el[row * HEADS + h] = pel;
                        er[row * HEADS + h] = per;
                    }
                }
            }
        }
    }
}

// ---------------- layer-2 attention dot products ----------------

__global__ __launch_bounds__(64) void elr2_kernel(const float* __restrict__ feat,
                                                  const float* __restrict__ al,
                                                  const float* __restrict__ ar,
                                                  float* __restrict__ el,
                                                  float* __restrict__ er) {
    int n = blockIdx.x, d = threadIdx.x;
    float f = feat[(size_t)n * 64 + d];
    float a = f * al[d], b = f * ar[d];
    #pragma unroll
    for (int o = 32; o; o >>= 1) { a += __shfl_xor(a, o); b += __shfl_xor(b, o); }
    if (d == 0) { el[n] = a; er[n] = b; }
}

// ---------------- softmax weights (alpha) per edge ----------------

__global__ __launch_bounds__(256) void alpha1_kernel(const float4* __restrict__ el,
                                                     const float4* __restrict__ er,
                                                     const int* __restrict__ offs,
                                                     const int* __restrict__ ssorted,
                                                     float4* __restrict__ alpha) {
    int n = blockIdx.x * 4 + (threadIdx.x >> 6);
    int l = threadIdx.x & 63;
    int start = offs[n], end = offs[n + 1];
    if (start == end) return;
    float4 ern = er[n];
    float m0 = -INFINITY, m1 = -INFINITY, m2 = -INFINITY, m3 = -INFINITY;
    float s0 = 0.f, s1 = 0.f, s2 = 0.f, s3 = 0.f;
    for (int base = start; base + l < end; base += 64) {
        int sj = ssorted[base + l];
        float4 ev = el[sj];
        float e0 = ev.x + ern.x; e0 = e0 > 0.f ? e0 : NEG_SLOPE * e0;
        float e1 = ev.y + ern.y; e1 = e1 > 0.f ? e1 : NEG_SLOPE * e1;
        float e2 = ev.z + ern.z; e2 = e2 > 0.f ? e2 : NEG_SLOPE * e2;
        float e3 = ev.w + ern.w; e3 = e3 > 0.f ? e3 : NEG_SLOPE * e3;
        float nm;
        nm = fmaxf(m0, e0); s0 = (m0 == nm ? s0 : s0 * __expf(m0 - nm)) + __expf(e0 - nm); m0 = nm;
        nm = fmaxf(m1, e1); s1 = (m1 == nm ? s1 : s1 * __expf(m1 - nm)) + __expf(e1 - nm); m1 = nm;
        nm = fmaxf(m2, e2); s2 = (m2 == nm ? s2 : s2 * __expf(m2 - nm)) + __expf(e2 - nm); m2 = nm;
        nm = fmaxf(m3, e3); s3 = (m3 == nm ? s3 : s3 * __expf(m3 - nm)) + __expf(e3 - nm); m3 = nm;
    }
    #pragma unroll
    for (int o = 1; o < 64; o <<= 1) {
        float om, os, nm, sa, sb;
        om = __shfl_xor(m0, o); os = __shfl_xor(s0, o); nm = fmaxf(m0, om);
        sa = (m0 == nm) ? s0 : s0 * __expf(m0 - nm); sb = (om == nm) ? os : os * __expf(om - nm);
        m0 = nm; s0 = sa + sb;
        om = __shfl_xor(m1, o); os = __shfl_xor(s1, o); nm = fmaxf(m1, om);
        sa = (m1 == nm) ? s1 : s1 * __expf(m1 - nm); sb = (om == nm) ? os : os * __expf(om - nm);
        m1 = nm; s1 = sa + sb;
        om = __shfl_xor(m2, o); os = __shfl_xor(s2, o); nm = fmaxf(m2, om);
        sa = (m2 == nm) ? s2 : s2 * __expf(m2 - nm); sb = (om == nm) ? os : os * __expf(om - nm);
        m2 = nm; s2 = sa + sb;
        om = __shfl_xor(m3, o); os = __shfl_xor(s3, o); nm = fmaxf(m3, om);
        sa = (m3 == nm) ? s3 : s3 * __expf(m3 - nm); sb = (om == nm) ? os : os * __expf(om - nm);
        m3 = nm; s3 = sa + sb;
    }
    float r0 = 1.f / s0, r1 = 1.f / s1, r2 = 1.f / s2, r3 = 1.f / s3;
    for (int base = start; base + l < end; base += 64) {
        int sj = ssorted[base + l];
        float4 ev = el[sj];
        float e0 = ev.x + ern.x; e0 = e0 > 0.f ? e0 : NEG_SLOPE * e0;
        float e1 = ev.y + ern.y; e1 = e1 > 0.f ? e1 : NEG_SLOPE * e1;
        float e2 = ev.z + ern.z; e2 = e2 > 0.f ? e2 : NEG_SLOPE * e2;
        float e3 = ev.w + ern.w; e3 = e3 > 0.f ? e3 : NEG_SLOPE * e3;
        float4 a;
        a.x = __expf(e0 - m0) * r0;
        a.y = __expf(e1 - m1) * r1;
        a.z = __expf(e2 - m2) * r2;
        a.w = __expf(e3 - m3) * r3;
        alpha[base + l] = a;
    }
}

__global__ __launch_bounds__(256) void alpha2_kernel(const float* __restrict__ el,
                                                     const float* __restrict__ er,
                                                     const int* __restrict__ offs,
                                                     const int* __restrict__ ssorted,
                                                     float* __restrict__ alpha) {
    int n = blockIdx.x * 4 + (threadIdx.x >> 6);
    int l = threadIdx.x & 63;
    int start = offs[n], end = offs[n + 1];
    if (start == end) return;
    float ern = er[n];
    float m = -INFINITY, s = 0.f;
    for (int base = start; base + l < end; base += 64) {
        int sj = ssorted[base + l];
        float e = el[sj] + ern; e = e > 0.f ? e : NEG_SLOPE * e;
        float nm = fmaxf(m, e);
        s = (m == nm ? s : s * __expf(m - nm)) + __expf(e - nm);
        m = nm;
    }
    #pragma unroll
    for (int o = 1; o < 64; o <<= 1) {
        float om = __shfl_xor(m, o), os = __shfl_xor(s, o);
        float nm = fmaxf(m, om);
        float sa = (m == nm) ? s : s * __expf(m - nm);
        float sb = (om == nm) ? os : os * __expf(om - nm);
        m = nm; s = sa + sb;
    }
    float r = 1.f / s;
    for (int base = start; base + l < end; base += 64) {
        int sj = ssorted[base + l];
        float e = el[sj] + ern; e = e > 0.f ? e : NEG_SLOPE * e;
        alpha[base + l] = __expf(e - m) * r;
    }
}

// ---------------- weighted aggregation (SpMM) ----------------
// Layer 1: block = 1 node, 4 waves. Wave g handles edges start+g (mod 4),
// unrolled x4 -> 4 independent 1KB row-gathers in flight per wave (16/block).
// Emits h1 as split-bf16 hi/lo for GEMM2.

__global__ __launch_bounds__(256) void spmm1_kernel(const float4* __restrict__ feat,
                                                    const float* __restrict__ alpha,
                                                    const int* __restrict__ offs,
                                                    const int* __restrict__ ssorted,
                                                    unsigned short* __restrict__ h1hi,
                                                    unsigned short* __restrict__ h1lo) {
    __shared__ float4 red[3][64];
    int n = blockIdx.x;
    int g = threadIdx.x >> 6, l = threadIdx.x & 63;
    int h = l >> 4;
    int start = offs[n], end = offs[n + 1];
    float4 acc = {0.f, 0.f, 0.f, 0.f};
    int pos = start + g;
    for (; pos + 12 < end; pos += 16) {
        int s0 = ssorted[pos], s1 = ssorted[pos + 4],
            s2 = ssorted[pos + 8], s3 = ssorted[pos + 12];
        float a0 = alpha[pos * 4 + h], a1 = alpha[(pos + 4) * 4 + h],
              a2 = alpha[(pos + 8) * 4 + h], a3 = alpha[(pos + 12) * 4 + h];
        float4 f0 = feat[(size_t)s0 * 64 + l];
        float4 f1 = feat[(size_t)s1 * 64 + l];
        float4 f2 = feat[(size_t)s2 * 64 + l];
        float4 f3 = feat[(size_t)s3 * 64 + l];
        acc.x = fmaf(a0, f0.x, acc.x); acc.y = fmaf(a0, f0.y, acc.y);
        acc.z = fmaf(a0, f0.z, acc.z); acc.w = fmaf(a0, f0.w, acc.w);
        acc.x = fmaf(a1, f1.x, acc.x); acc.y = fmaf(a1, f1.y, acc.y);
        acc.z = fmaf(a1, f1.z, acc.z); acc.w = fmaf(a1, f1.w, acc.w);
        acc.x = fmaf(a2, f2.x, acc.x); acc.y = fmaf(a2, f2.y, acc.y);
        acc.z = fmaf(a2, f2.z, acc.z); acc.w = fmaf(a2, f2.w, acc.w);
        acc.x = fmaf(a3, f3.x, acc.x); acc.y = fmaf(a3, f3.y, acc.y);
        acc.z = fmaf(a3, f3.z, acc.z); acc.w = fmaf(a3, f3.w, acc.w);
    }
    for (; pos < end; pos += 4) {
        int s = ssorted[pos];
        float a = alpha[pos * 4 + h];
        float4 f = feat[(size_t)s * 64 + l];
        acc.x = fmaf(a, f.x, acc.x);
        acc.y = fmaf(a, f.y, acc.y);
        acc.z = fmaf(a, f.z, acc.z);
        acc.w = fmaf(a, f.w, acc.w);
    }
    if (g) red[g - 1][l] = acc;
    __syncthreads();
    if (!g) {
        float4 b0 = red[0][l], b1 = red[1][l], b2 = red[2][l];
        acc.x += b0.x + b1.x + b2.x;
        acc.y += b0.y + b1.y + b2.y;
        acc.z += b0.z + b1.z + b2.z;
        acc.w += b0.w + b1.w + b2.w;
        acc.x = acc.x > 0.f ? acc.x : __expf(acc.x) - 1.f;   // ELU
        acc.y = acc.y > 0.f ? acc.y : __expf(acc.y) - 1.f;
        acc.z = acc.z > 0.f ? acc.z : __expf(acc.z) - 1.f;
        acc.w = acc.w > 0.f ? acc.w : __expf(acc.w) - 1.f;
        unsigned short h0 = bf16_rtn(acc.x), h1 = bf16_rtn(acc.y),
                       h2 = bf16_rtn(acc.z), h3 = bf16_rtn(acc.w);
        ushort4 hv = make_ushort4(h0, h1, h2, h3);
        ushort4 lv = make_ushort4(bf16_rtn(acc.x - bf16_to_f32(h0)),
                                  bf16_rtn(acc.y - bf16_to_f32(h1)),
                                  bf16_rtn(acc.z - bf16_to_f32(h2)),
                                  bf16_rtn(acc.w - bf16_to_f32(h3)));
        *(ushort4*)&h1hi[(size_t)n * 256 + l * 4] = hv;
        *(ushort4*)&h1lo[(size_t)n * 256 + l * 4] = lv;
    }
}

// Layer 2: 16 subgroups of 16 lanes, x2 unroll -> 32 row-gathers in flight.

__global__ __launch_bounds__(256) void spmm2_kernel(const float4* __restrict__ feat,
                                                    const float* __restrict__ alpha,
                                                    const int* __restrict__ offs,
                                                    const int* __restrict__ ssorted,
                                                    float4* __restrict__ out) {
    __shared__ float4 red[3][16];
    int n = blockIdx.x;
    int g = threadIdx.x >> 6, l = threadIdx.x & 63;
    int sub = l >> 4, li = l & 15;
    int start = offs[n], end = offs[n + 1];
    float4 acc = {0.f, 0.f, 0.f, 0.f};
    int pos = start + g * 4 + sub;
    for (; pos + 16 < end; pos += 32) {
        int s0 = ssorted[pos], s1 = ssorted[pos + 16];
        float a0 = alpha[pos], a1 = alpha[pos + 16];
        float4 f0 = feat[(size_t)s0 * 16 + li];
        float4 f1 = feat[(size_t)s1 * 16 + li];
        acc.x = fmaf(a0, f0.x, acc.x); acc.y = fmaf(a0, f0.y, acc.y);
        acc.z = fmaf(a0, f0.z, acc.z); acc.w = fmaf(a0, f0.w, acc.w);
        acc.x = fmaf(a1, f1.x, acc.x); acc.y = fmaf(a1, f1.y, acc.y);
        acc.z = fmaf(a1, f1.z, acc.z); acc.w = fmaf(a1, f1.w, acc.w);
    }
    for (; pos < end; pos += 16) {
        int s = ssorted[pos];
        float a = alpha[pos];
        float4 f = feat[(size_t)s * 16 + li];
        acc.x = fmaf(a, f.x, acc.x);
        acc.y = fmaf(a, f.y, acc.y);
        acc.z = fmaf(a, f.z, acc.z);
        acc.w = fmaf(a, f.w, acc.w);
    }
    #pragma unroll
    for (int o = 16; o < 64; o <<= 1) {
        acc.x += __shfl_xor(acc.x, o);
        acc.y += __shfl_xor(acc.y, o);
        acc.z += __shfl_xor(acc.z, o);
        acc.w += __shfl_xor(acc.w, o);
    }
    if (g && sub == 0) red[g - 1][li] = acc;
    __syncthreads();
    if (!g && sub == 0) {
        float4 b0 = red[0][li], b1 = red[1][li], b2 = red[2][li];
        acc.x += b0.x + b1.x + b2.x;
        acc.y += b0.y + b1.y + b2.y;
        acc.z += b0.z + b1.z + b2.z;
        acc.w += b0.w + b1.w + b2.w;
        out[(size_t)n * 16 + li] = acc;
    }
}

// ---------------- launch ----------------

extern "C" void kernel_launch(void* const* d_in, const int* in_sizes, int n_in,
                              void* d_out, int out_size, void* d_ws, size_t ws_size,
                              hipStream_t stream) {
    const float* x   = (const float*)d_in[0];
    const int*   src = (const int*)d_in[1];
    const int*   dst = (const int*)d_in[2];
    const float* W1  = (const float*)d_in[3];
    const float* al1 = (const float*)d_in[4];
    const float* ar1 = (const float*)d_in[5];
    const float* W2  = (const float*)d_in[6];
    const float* al2 = (const float*)d_in[7];
    const float* ar2 = (const float*)d_in[8];
    float* out = (float*)d_out;

    char* ws = (char*)d_ws;
    size_t off = 0;
    auto alloc = [&](size_t bytes) -> void* {
        void* p = ws + off;
        off += (bytes + 255) & ~(size_t)255;
        return p;
    };
    float* feat1  = (float*)alloc((size_t)NNODES * 256 * 4);                  // 51.2 MB
    unsigned short* h1hi = (unsigned short*)alloc((size_t)NNODES * 256 * 2);  // 25.6 MB
    unsigned short* h1lo = (unsigned short*)alloc((size_t)NNODES * 256 * 2);  // 25.6 MB
    unsigned short* W1hi = (unsigned short*)alloc((size_t)256 * 256 * 2);
    unsigned short* W1lo = (unsigned short*)alloc((size_t)256 * 256 * 2);
    unsigned short* W2hi = (unsigned short*)alloc((size_t)64 * 256 * 2);
    unsigned short* W2lo = (unsigned short*)alloc((size_t)64 * 256 * 2);
    float* el1    = (float*)alloc((size_t)NNODES * HEADS * 4);
    float* er1    = (float*)alloc((size_t)NNODES * HEADS * 4);
    float* el2    = (float*)alloc((size_t)NNODES * 4);
    float* er2    = (float*)alloc((size_t)NNODES * 4);
    float* alpha1 = (float*)alloc((size_t)NEDGES * HEADS * 4);                // 12.8 MB
    float* alpha2 = (float*)alloc((size_t)NEDGES * 4);                        // 3.2 MB
    int* deg      = (int*)alloc((size_t)NNODES * 4);
    int* cursor   = (int*)alloc((size_t)NNODES * 4);
    int* offs     = (int*)alloc((size_t)(NNODES + 1) * 4);
    int* ssorted  = (int*)alloc((size_t)NEDGES * 4);
    float* feat2  = feat1;   // feat1 dead after spmm1

    // --- CSR build ---
    hipMemsetAsync(deg, 0, (size_t)NNODES * 4, stream);
    hipMemsetAsync(cursor, 0, (size_t)NNODES * 4, stream);
    hist_kernel<<<(NEDGES + 255) / 256, 256, 0, stream>>>(dst, deg);
    scan_kernel<<<1, 1024, 0, stream>>>(deg, offs);
    scatter_kernel<<<(NEDGES + 255) / 256, 256, 0, stream>>>(src, dst, offs, cursor, ssorted);

    // --- weight conversions ---
    convert_wt_kernel<<<(256 * 256 + 255) / 256, 256, 0, stream>>>(W1, W1hi, W1lo, 256, 256);
    convert_wt_kernel<<<(256 * 64 + 255) / 256, 256, 0, stream>>>(W2, W2hi, W2lo, 256, 64);

    // --- Layer 1: GEMM (inline split of fp32 x) + fused el/er epilogue ---
    gemm_mfma_kernel<128, false, true><<<dim3(256 / 128, (NNODES + 127) / 128), 256, 0, stream>>>(
        x, nullptr, nullptr, W1hi, W1lo, feat1, al1, ar1, el1, er1, NNODES, 256, 256);
    alpha1_kernel<<<NNODES / 4, 256, 0, stream>>>(
        (const float4*)el1, (const float4*)er1, offs, ssorted, (float4*)alpha1);
    spmm1_kernel<<<NNODES, 256, 0, stream>>>(
        (const float4*)feat1, alpha1, offs, ssorted, h1hi, h1lo);

    // --- Layer 2 ---
    gemm_mfma_kernel<64, true, false><<<dim3(64 / 64, (NNODES + 127) / 128), 256, 0, stream>>>(
        nullptr, h1hi, h1lo, W2hi, W2lo, feat2, nullptr, nullptr, nullptr, nullptr, NNODES, 64, 256);
    elr2_kernel<<<NNODES, 64, 0, stream>>>(feat2, al2, ar2, el2, er2);
    alpha2_kernel<<<NNODES / 4, 256, 0, stream>>>(el2, er2, offs, ssorted, alpha2);
    spmm2_kernel<<<NNODES, 256, 0, stream>>>(
        (const float4*)feat2, alpha2, offs, ssorted, (float4*)out);
}

// Round 5
// 535.150 us; speedup vs baseline: 1.2901x; 1.0967x over previous
//
#include <hip/hip_runtime.h>
#include <math.h>

#define NNODES 50000
#define NEDGES 800000
#define INDIM 256
#define HID 64
#define HEADS 4
#define OUTDIM 64
#define NEG_SLOPE 0.2f

typedef __attribute__((ext_vector_type(8))) short short8;   // 8 bf16 = 4 VGPRs
typedef __attribute__((ext_vector_type(8))) unsigned short ushort8;
typedef __attribute__((ext_vector_type(4))) float f32x4;
typedef _Float16 __attribute__((ext_vector_type(4))) half4;

__device__ inline unsigned short bf16_rtn(float f) {
    unsigned int u = __float_as_uint(f);
    unsigned int r = u + 0x7fffu + ((u >> 16) & 1u);
    return (unsigned short)(r >> 16);
}
__device__ inline float bf16_to_f32(unsigned short h) {
    return __uint_as_float((unsigned int)h << 16);
}

// ---------------- CSR build ----------------

__global__ __launch_bounds__(256) void hist_kernel(const int* __restrict__ dst,
                                                   int* __restrict__ deg) {
    int i = blockIdx.x * 256 + threadIdx.x;
    if (i < NEDGES) atomicAdd(&deg[dst[i]], 1);
}

__global__ __launch_bounds__(1024) void scan_kernel(const int* __restrict__ deg,
                                                    int* __restrict__ offs) {
    const int n = NNODES;
    int t = threadIdx.x;
    int lane = t & 63, wid = t >> 6;
    const int per = (n + 1023) / 1024;  // 49
    int s0 = t * per;
    int sum = 0;
    for (int i = 0; i < per; ++i) { int idx = s0 + i; if (idx < n) sum += deg[idx]; }
    int v = sum;
    #pragma unroll
    for (int o = 1; o < 64; o <<= 1) { int u = __shfl_up(v, o); if (lane >= o) v += u; }
    __shared__ int wsum[16];
    if (lane == 63) wsum[wid] = v;
    __syncthreads();
    if (t < 16) {
        int wv = wsum[t];
        #pragma unroll
        for (int o = 1; o < 16; o <<= 1) { int u = __shfl_up(wv, o); if (t >= o) wv += u; }
        wsum[t] = wv;
    }
    __syncthreads();
    int waveoff = (wid == 0) ? 0 : wsum[wid - 1];
    int run = waveoff + v - sum;
    for (int i = 0; i < per; ++i) {
        int idx = s0 + i;
        if (idx < n) { offs[idx] = run; run += deg[idx]; }
    }
    if (t == 1023) offs[n] = run;
}

__global__ __launch_bounds__(256) void scatter_kernel(const int* __restrict__ src,
                                                      const int* __restrict__ dst,
                                                      const int* __restrict__ offs,
                                                      int* __restrict__ cursor,
                                                      int* __restrict__ ssorted) {
    int i = blockIdx.x * 256 + threadIdx.x;
    if (i < NEDGES) {
        int d = dst[i];
        int pos = offs[d] + atomicAdd(&cursor[d], 1);
        ssorted[pos] = src[i];
    }
}

// ---------------- weight transpose+split ----------------
// W [K][N] row-major -> transposed split Wt_hi/Wt_lo [N][K]

__global__ __launch_bounds__(256) void convert_wt_kernel(const float* __restrict__ W,
                                                         unsigned short* __restrict__ hi,
                                                         unsigned short* __restrict__ lo,
                                                         int K, int N) {
    int idx = blockIdx.x * 256 + threadIdx.x;
    if (idx >= K * N) return;
    int k = idx / N, n = idx - k * N;
    float v = W[idx];
    unsigned short h = bf16_rtn(v);
    hi[n * K + k] = h;
    lo[n * K + k] = bf16_rtn(v - bf16_to_f32(h));
}

// ---------------- split-bf16 MFMA GEMM ----------------
// C[M,N] = A @ Bt^T with Bt [N][K] pre-split bf16. A either fp32 [M,K]
// (SPLITA=false, split inline during staging) or pre-split hi/lo bf16.
// BM=128, BK=32, 4 waves 2x2, 3 MFMA products (hh, hl, lh). C stored fp16.
// ELR (BN=128 only): each wave's 64 cols = one head -> fused el/er epilogue.

template <int BN, bool SPLITA, bool ELR>
__global__ __launch_bounds__(256) void gemm_mfma_kernel(
        const float* __restrict__ Af,
        const unsigned short* __restrict__ Ahi, const unsigned short* __restrict__ Alo,
        const unsigned short* __restrict__ Bthi, const unsigned short* __restrict__ Btlo,
        _Float16* __restrict__ C,
        const float* __restrict__ al, const float* __restrict__ ar,
        float* __restrict__ el, float* __restrict__ er,
        int M, int N, int K) {
    constexpr int NT = BN / 32;       // n-tiles per wave
    constexpr int PB = BN / 64;       // B staging passes
    __shared__ unsigned short As_hi[128 * 40], As_lo[128 * 40];
    __shared__ unsigned short Bs_hi[BN * 40], Bs_lo[BN * 40];
    int t = threadIdx.x;
    int lane = t & 63, w = t >> 6;
    int wm = w >> 1, wn = w & 1;
    int lr = lane & 15, quad = lane >> 4;
    int m0 = blockIdx.y * 128, n0 = blockIdx.x * BN;

    f32x4 acc[4][NT];
    #pragma unroll
    for (int i = 0; i < 4; ++i)
        #pragma unroll
        for (int j = 0; j < NT; ++j) acc[i][j] = (f32x4){0.f, 0.f, 0.f, 0.f};

    int srow = t >> 2, schunk = t & 3;  // staging: row / 8-elem chunk

    for (int kk = 0; kk < K; kk += 32) {
        uint4 rah[2], ral[2], rbh[PB], rbl[PB];
        float4 fa[2][2];
        #pragma unroll
        for (int p = 0; p < 2; ++p) {
            int row = srow + p * 64;
            int gr = m0 + row;
            if (SPLITA) {
                if (gr < M) {
                    size_t off = (size_t)gr * K + kk + schunk * 8;
                    rah[p] = *(const uint4*)(Ahi + off);
                    ral[p] = *(const uint4*)(Alo + off);
                } else {
                    rah[p] = make_uint4(0, 0, 0, 0);
                    ral[p] = make_uint4(0, 0, 0, 0);
                }
            } else {
                if (gr < M) {
                    size_t off = (size_t)gr * K + kk + schunk * 8;
                    fa[p][0] = *(const float4*)(Af + off);
                    fa[p][1] = *(const float4*)(Af + off + 4);
                } else {
                    fa[p][0] = make_float4(0.f, 0.f, 0.f, 0.f);
                    fa[p][1] = make_float4(0.f, 0.f, 0.f, 0.f);
                }
            }
        }
        #pragma unroll
        for (int p = 0; p < PB; ++p) {
            int row = srow + p * 64;
            size_t off = (size_t)(n0 + row) * K + kk + schunk * 8;
            rbh[p] = *(const uint4*)(Bthi + off);
            rbl[p] = *(const uint4*)(Btlo + off);
        }
        __syncthreads();
        #pragma unroll
        for (int p = 0; p < 2; ++p) {
            int row = srow + p * 64;
            if (SPLITA) {
                *(uint4*)(As_hi + row * 40 + schunk * 8) = rah[p];
                *(uint4*)(As_lo + row * 40 + schunk * 8) = ral[p];
            } else {
                float v[8] = {fa[p][0].x, fa[p][0].y, fa[p][0].z, fa[p][0].w,
                              fa[p][1].x, fa[p][1].y, fa[p][1].z, fa[p][1].w};
                ushort8 hv, lv;
                #pragma unroll
                for (int e = 0; e < 8; ++e) {
                    unsigned short h = bf16_rtn(v[e]);
                    hv[e] = (short)h;
                    lv[e] = (short)bf16_rtn(v[e] - bf16_to_f32(h));
                }
                *(ushort8*)(As_hi + row * 40 + schunk * 8) = hv;
                *(ushort8*)(As_lo + row * 40 + schunk * 8) = lv;
            }
        }
        #pragma unroll
        for (int p = 0; p < PB; ++p) {
            int row = srow + p * 64;
            *(uint4*)(Bs_hi + row * 40 + schunk * 8) = rbh[p];
            *(uint4*)(Bs_lo + row * 40 + schunk * 8) = rbl[p];
        }
        __syncthreads();

        short8 ah[4], alo[4], bh[NT], blo[NT];
        #pragma unroll
        for (int i = 0; i < 4; ++i) {
            int r = wm * 64 + i * 16 + lr;
            ah[i]  = *(const short8*)(As_hi + r * 40 + quad * 8);
            alo[i] = *(const short8*)(As_lo + r * 40 + quad * 8);
        }
        #pragma unroll
        for (int j = 0; j < NT; ++j) {
            int r = wn * NT * 16 + j * 16 + lr;
            bh[j]  = *(const short8*)(Bs_hi + r * 40 + quad * 8);
            blo[j] = *(const short8*)(Bs_lo + r * 40 + quad * 8);
        }
        #pragma unroll
        for (int i = 0; i < 4; ++i)
            #pragma unroll
            for (int j = 0; j < NT; ++j) {
                acc[i][j] = __builtin_amdgcn_mfma_f32_16x16x32_bf16(ah[i], bh[j], acc[i][j], 0, 0, 0);
                acc[i][j] = __builtin_amdgcn_mfma_f32_16x16x32_bf16(ah[i], blo[j], acc[i][j], 0, 0, 0);
                acc[i][j] = __builtin_amdgcn_mfma_f32_16x16x32_bf16(alo[i], bh[j], acc[i][j], 0, 0, 0);
            }
        __syncthreads();
    }
    #pragma unroll
    for (int i = 0; i < 4; ++i) {
        #pragma unroll
        for (int r = 0; r < 4; ++r) {
            int row = m0 + wm * 64 + i * 16 + quad * 4 + r;
            if (row < M) {
                #pragma unroll
                for (int j = 0; j < NT; ++j)
                    C[(size_t)row * N + n0 + wn * NT * 16 + j * 16 + lr] =
                        (_Float16)acc[i][j][r];
            }
        }
    }
    if (ELR) {
        // wave (wm,wn) covers head h = n0/64 + wn, rows [m0+wm*64, +64)
        int h = n0 / 64 + wn;
        float alh[NT], arh[NT];
        #pragma unroll
        for (int j = 0; j < NT; ++j) {
            alh[j] = al[h * 64 + j * 16 + lr];
            arh[j] = ar[h * 64 + j * 16 + lr];
        }
        #pragma unroll
        for (int i = 0; i < 4; ++i) {
            #pragma unroll
            for (int r = 0; r < 4; ++r) {
                float pel = 0.f, per = 0.f;
                #pragma unroll
                for (int j = 0; j < NT; ++j) {
                    pel = fmaf(acc[i][j][r], alh[j], pel);
                    per = fmaf(acc[i][j][r], arh[j], per);
                }
                #pragma unroll
                for (int o = 1; o < 16; o <<= 1) {
                    pel += __shfl_xor(pel, o);
                    per += __shfl_xor(per, o);
                }
                if (lr == 0) {
                    int row = m0 + wm * 64 + i * 16 + quad * 4 + r;
                    if (row < M) {
                        el[row * HEADS + h] = pel;
                        er[row * HEADS + h] = per;
                    }
                }
            }
        }
    }
}

// ---------------- layer-2 attention dot products ----------------

__global__ __launch_bounds__(64) void elr2_kernel(const _Float16* __restrict__ feat,
                                                  const float* __restrict__ al,
                                                  const float* __restrict__ ar,
                                                  float* __restrict__ el,
                                                  float* __restrict__ er) {
    int n = blockIdx.x, d = threadIdx.x;
    float f = (float)feat[(size_t)n * 64 + d];
    float a = f * al[d], b = f * ar[d];
    #pragma unroll
    for (int o = 32; o; o >>= 1) { a += __shfl_xor(a, o); b += __shfl_xor(b, o); }
    if (d == 0) { el[n] = a; er[n] = b; }
}

// ---------------- softmax weights (alpha) per edge ----------------

__global__ __launch_bounds__(256) void alpha1_kernel(const float4* __restrict__ el,
                                                     const float4* __restrict__ er,
                                                     const int* __restrict__ offs,
                                                     const int* __restrict__ ssorted,
                                                     float4* __restrict__ alpha) {
    int n = blockIdx.x * 4 + (threadIdx.x >> 6);
    int l = threadIdx.x & 63;
    int start = offs[n], end = offs[n + 1];
    if (start == end) return;
    float4 ern = er[n];
    float m0 = -INFINITY, m1 = -INFINITY, m2 = -INFINITY, m3 = -INFINITY;
    float s0 = 0.f, s1 = 0.f, s2 = 0.f, s3 = 0.f;
    for (int base = start; base + l < end; base += 64) {
        int sj = ssorted[base + l];
        float4 ev = el[sj];
        float e0 = ev.x + ern.x; e0 = e0 > 0.f ? e0 : NEG_SLOPE * e0;
        float e1 = ev.y + ern.y; e1 = e1 > 0.f ? e1 : NEG_SLOPE * e1;
        float e2 = ev.z + ern.z; e2 = e2 > 0.f ? e2 : NEG_SLOPE * e2;
        float e3 = ev.w + ern.w; e3 = e3 > 0.f ? e3 : NEG_SLOPE * e3;
        float nm;
        nm = fmaxf(m0, e0); s0 = (m0 == nm ? s0 : s0 * __expf(m0 - nm)) + __expf(e0 - nm); m0 = nm;
        nm = fmaxf(m1, e1); s1 = (m1 == nm ? s1 : s1 * __expf(m1 - nm)) + __expf(e1 - nm); m1 = nm;
        nm = fmaxf(m2, e2); s2 = (m2 == nm ? s2 : s2 * __expf(m2 - nm)) + __expf(e2 - nm); m2 = nm;
        nm = fmaxf(m3, e3); s3 = (m3 == nm ? s3 : s3 * __expf(m3 - nm)) + __expf(e3 - nm); m3 = nm;
    }
    #pragma unroll
    for (int o = 1; o < 64; o <<= 1) {
        float om, os, nm, sa, sb;
        om = __shfl_xor(m0, o); os = __shfl_xor(s0, o); nm = fmaxf(m0, om);
        sa = (m0 == nm) ? s0 : s0 * __expf(m0 - nm); sb = (om == nm) ? os : os * __expf(om - nm);
        m0 = nm; s0 = sa + sb;
        om = __shfl_xor(m1, o); os = __shfl_xor(s1, o); nm = fmaxf(m1, om);
        sa = (m1 == nm) ? s1 : s1 * __expf(m1 - nm); sb = (om == nm) ? os : os * __expf(om - nm);
        m1 = nm; s1 = sa + sb;
        om = __shfl_xor(m2, o); os = __shfl_xor(s2, o); nm = fmaxf(m2, om);
        sa = (m2 == nm) ? s2 : s2 * __expf(m2 - nm); sb = (om == nm) ? os : os * __expf(om - nm);
        m2 = nm; s2 = sa + sb;
        om = __shfl_xor(m3, o); os = __shfl_xor(s3, o); nm = fmaxf(m3, om);
        sa = (m3 == nm) ? s3 : s3 * __expf(m3 - nm); sb = (om == nm) ? os : os * __expf(om - nm);
        m3 = nm; s3 = sa + sb;
    }
    float r0 = 1.f / s0, r1 = 1.f / s1, r2 = 1.f / s2, r3 = 1.f / s3;
    for (int base = start; base + l < end; base += 64) {
        int sj = ssorted[base + l];
        float4 ev = el[sj];
        float e0 = ev.x + ern.x; e0 = e0 > 0.f ? e0 : NEG_SLOPE * e0;
        float e1 = ev.y + ern.y; e1 = e1 > 0.f ? e1 : NEG_SLOPE * e1;
        float e2 = ev.z + ern.z; e2 = e2 > 0.f ? e2 : NEG_SLOPE * e2;
        float e3 = ev.w + ern.w; e3 = e3 > 0.f ? e3 : NEG_SLOPE * e3;
        float4 a;
        a.x = __expf(e0 - m0) * r0;
        a.y = __expf(e1 - m1) * r1;
        a.z = __expf(e2 - m2) * r2;
        a.w = __expf(e3 - m3) * r3;
        alpha[base + l] = a;
    }
}

__global__ __launch_bounds__(256) void alpha2_kernel(const float* __restrict__ el,
                                                     const float* __restrict__ er,
                                                     const int* __restrict__ offs,
                                                     const int* __restrict__ ssorted,
                                                     float* __restrict__ alpha) {
    int n = blockIdx.x * 4 + (threadIdx.x >> 6);
    int l = threadIdx.x & 63;
    int start = offs[n], end = offs[n + 1];
    if (start == end) return;
    float ern = er[n];
    float m = -INFINITY, s = 0.f;
    for (int base = start; base + l < end; base += 64) {
        int sj = ssorted[base + l];
        float e = el[sj] + ern; e = e > 0.f ? e : NEG_SLOPE * e;
        float nm = fmaxf(m, e);
        s = (m == nm ? s : s * __expf(m - nm)) + __expf(e - nm);
        m = nm;
    }
    #pragma unroll
    for (int o = 1; o < 64; o <<= 1) {
        float om = __shfl_xor(m, o), os = __shfl_xor(s, o);
        float nm = fmaxf(m, om);
        float sa = (m == nm) ? s : s * __expf(m - nm);
        float sb = (om == nm) ? os : os * __expf(om - nm);
        m = nm; s = sa + sb;
    }
    float r = 1.f / s;
    for (int base = start; base + l < end; base += 64) {
        int sj = ssorted[base + l];
        float e = el[sj] + ern; e = e > 0.f ? e : NEG_SLOPE * e;
        alpha[base + l] = __expf(e - m) * r;
    }
}

// ---------------- weighted aggregation (SpMM), fp16 feature gather ----------
// Layer 1: block = 1 node, 4 waves, x4 unroll -> 16 rows (512B each) in
// flight. Lane l holds cols 4l..4l+3 (half4 = 8B). Emits h1 split-bf16.

__global__ __launch_bounds__(256) void spmm1_kernel(const half4* __restrict__ feat,
                                                    const float* __restrict__ alpha,
                                                    const int* __restrict__ offs,
                                                    const int* __restrict__ ssorted,
                                                    unsigned short* __restrict__ h1hi,
                                                    unsigned short* __restrict__ h1lo) {
    __shared__ float4 red[3][64];
    int n = blockIdx.x;
    int g = threadIdx.x >> 6, l = threadIdx.x & 63;
    int h = l >> 4;
    int start = offs[n], end = offs[n + 1];
    float4 acc = {0.f, 0.f, 0.f, 0.f};
    int pos = start + g;
    for (; pos + 12 < end; pos += 16) {
        int s0 = ssorted[pos], s1 = ssorted[pos + 4],
            s2 = ssorted[pos + 8], s3 = ssorted[pos + 12];
        float a0 = alpha[pos * 4 + h], a1 = alpha[(pos + 4) * 4 + h],
              a2 = alpha[(pos + 8) * 4 + h], a3 = alpha[(pos + 12) * 4 + h];
        half4 f0 = feat[(size_t)s0 * 64 + l];
        half4 f1 = feat[(size_t)s1 * 64 + l];
        half4 f2 = feat[(size_t)s2 * 64 + l];
        half4 f3 = feat[(size_t)s3 * 64 + l];
        acc.x = fmaf(a0, (float)f0[0], acc.x); acc.y = fmaf(a0, (float)f0[1], acc.y);
        acc.z = fmaf(a0, (float)f0[2], acc.z); acc.w = fmaf(a0, (float)f0[3], acc.w);
        acc.x = fmaf(a1, (float)f1[0], acc.x); acc.y = fmaf(a1, (float)f1[1], acc.y);
        acc.z = fmaf(a1, (float)f1[2], acc.z); acc.w = fmaf(a1, (float)f1[3], acc.w);
        acc.x = fmaf(a2, (float)f2[0], acc.x); acc.y = fmaf(a2, (float)f2[1], acc.y);
        acc.z = fmaf(a2, (float)f2[2], acc.z); acc.w = fmaf(a2, (float)f2[3], acc.w);
        acc.x = fmaf(a3, (float)f3[0], acc.x); acc.y = fmaf(a3, (float)f3[1], acc.y);
        acc.z = fmaf(a3, (float)f3[2], acc.z); acc.w = fmaf(a3, (float)f3[3], acc.w);
    }
    for (; pos < end; pos += 4) {
        int s = ssorted[pos];
        float a = alpha[pos * 4 + h];
        half4 f = feat[(size_t)s * 64 + l];
        acc.x = fmaf(a, (float)f[0], acc.x);
        acc.y = fmaf(a, (float)f[1], acc.y);
        acc.z = fmaf(a, (float)f[2], acc.z);
        acc.w = fmaf(a, (float)f[3], acc.w);
    }
    if (g) red[g - 1][l] = acc;
    __syncthreads();
    if (!g) {
        float4 b0 = red[0][l], b1 = red[1][l], b2 = red[2][l];
        acc.x += b0.x + b1.x + b2.x;
        acc.y += b0.y + b1.y + b2.y;
        acc.z += b0.z + b1.z + b2.z;
        acc.w += b0.w + b1.w + b2.w;
        acc.x = acc.x > 0.f ? acc.x : __expf(acc.x) - 1.f;   // ELU
        acc.y = acc.y > 0.f ? acc.y : __expf(acc.y) - 1.f;
        acc.z = acc.z > 0.f ? acc.z : __expf(acc.z) - 1.f;
        acc.w = acc.w > 0.f ? acc.w : __expf(acc.w) - 1.f;
        unsigned short h0 = bf16_rtn(acc.x), h1 = bf16_rtn(acc.y),
                       h2 = bf16_rtn(acc.z), h3 = bf16_rtn(acc.w);
        ushort4 hv = make_ushort4(h0, h1, h2, h3);
        ushort4 lv = make_ushort4(bf16_rtn(acc.x - bf16_to_f32(h0)),
                                  bf16_rtn(acc.y - bf16_to_f32(h1)),
                                  bf16_rtn(acc.z - bf16_to_f32(h2)),
                                  bf16_rtn(acc.w - bf16_to_f32(h3)));
        *(ushort4*)&h1hi[(size_t)n * 256 + l * 4] = hv;
        *(ushort4*)&h1lo[(size_t)n * 256 + l * 4] = lv;
    }
}

// Layer 2: 16 subgroups of 16 lanes, x2 unroll -> 32 rows (128B) in flight.

__global__ __launch_bounds__(256) void spmm2_kernel(const half4* __restrict__ feat,
                                                    const float* __restrict__ alpha,
                                                    const int* __restrict__ offs,
                                                    const int* __restrict__ ssorted,
                                                    float4* __restrict__ out) {
    __shared__ float4 red[3][16];
    int n = blockIdx.x;
    int g = threadIdx.x >> 6, l = threadIdx.x & 63;
    int sub = l >> 4, li = l & 15;
    int start = offs[n], end = offs[n + 1];
    float4 acc = {0.f, 0.f, 0.f, 0.f};
    int pos = start + g * 4 + sub;
    for (; pos + 16 < end; pos += 32) {
        int s0 = ssorted[pos], s1 = ssorted[pos + 16];
        float a0 = alpha[pos], a1 = alpha[pos + 16];
        half4 f0 = feat[(size_t)s0 * 16 + li];
        half4 f1 = feat[(size_t)s1 * 16 + li];
        acc.x = fmaf(a0, (float)f0[0], acc.x); acc.y = fmaf(a0, (float)f0[1], acc.y);
        acc.z = fmaf(a0, (float)f0[2], acc.z); acc.w = fmaf(a0, (float)f0[3], acc.w);
        acc.x = fmaf(a1, (float)f1[0], acc.x); acc.y = fmaf(a1, (float)f1[1], acc.y);
        acc.z = fmaf(a1, (float)f1[2], acc.z); acc.w = fmaf(a1, (float)f1[3], acc.w);
    }
    for (; pos < end; pos += 16) {
        int s = ssorted[pos];
        float a = alpha[pos];
        half4 f = feat[(size_t)s * 16 + li];
        acc.x = fmaf(a, (float)f[0], acc.x);
        acc.y = fmaf(a, (float)f[1], acc.y);
        acc.z = fmaf(a, (float)f[2], acc.z);
        acc.w = fmaf(a, (float)f[3], acc.w);
    }
    #pragma unroll
    for (int o = 16; o < 64; o <<= 1) {
        acc.x += __shfl_xor(acc.x, o);
        acc.y += __shfl_xor(acc.y, o);
        acc.z += __shfl_xor(acc.z, o);
        acc.w += __shfl_xor(acc.w, o);
    }
    if (g && sub == 0) red[g - 1][li] = acc;
    __syncthreads();
    if (!g && sub == 0) {
        float4 b0 = red[0][li], b1 = red[1][li], b2 = red[2][li];
        acc.x += b0.x + b1.x + b2.x;
        acc.y += b0.y + b1.y + b2.y;
        acc.z += b0.z + b1.z + b2.z;
        acc.w += b0.w + b1.w + b2.w;
        out[(size_t)n * 16 + li] = acc;
    }
}

// ---------------- launch ----------------

extern "C" void kernel_launch(void* const* d_in, const int* in_sizes, int n_in,
                              void* d_out, int out_size, void* d_ws, size_t ws_size,
                              hipStream_t stream) {
    const float* x   = (const float*)d_in[0];
    const int*   src = (const int*)d_in[1];
    const int*   dst = (const int*)d_in[2];
    const float* W1  = (const float*)d_in[3];
    const float* al1 = (const float*)d_in[4];
    const float* ar1 = (const float*)d_in[5];
    const float* W2  = (const float*)d_in[6];
    const float* al2 = (const float*)d_in[7];
    const float* ar2 = (const float*)d_in[8];
    float* out = (float*)d_out;

    char* ws = (char*)d_ws;
    size_t off = 0;
    auto alloc = [&](size_t bytes) -> void* {
        void* p = ws + off;
        off += (bytes + 255) & ~(size_t)255;
        return p;
    };
    _Float16* feat1 = (_Float16*)alloc((size_t)NNODES * 256 * 2);             // 25.6 MB
    unsigned short* h1hi = (unsigned short*)alloc((size_t)NNODES * 256 * 2);  // 25.6 MB
    unsigned short* h1lo = (unsigned short*)alloc((size_t)NNODES * 256 * 2);  // 25.6 MB
    unsigned short* W1hi = (unsigned short*)alloc((size_t)256 * 256 * 2);
    unsigned short* W1lo = (unsigned short*)alloc((size_t)256 * 256 * 2);
    unsigned short* W2hi = (unsigned short*)alloc((size_t)64 * 256 * 2);
    unsigned short* W2lo = (unsigned short*)alloc((size_t)64 * 256 * 2);
    float* el1    = (float*)alloc((size_t)NNODES * HEADS * 4);
    float* er1    = (float*)alloc((size_t)NNODES * HEADS * 4);
    float* el2    = (float*)alloc((size_t)NNODES * 4);
    float* er2    = (float*)alloc((size_t)NNODES * 4);
    float* alpha1 = (float*)alloc((size_t)NEDGES * HEADS * 4);                // 12.8 MB
    float* alpha2 = (float*)alloc((size_t)NEDGES * 4);                        // 3.2 MB
    int* deg      = (int*)alloc((size_t)NNODES * 4);
    int* cursor   = (int*)alloc((size_t)NNODES * 4);
    int* offs     = (int*)alloc((size_t)(NNODES + 1) * 4);
    int* ssorted  = (int*)alloc((size_t)NEDGES * 4);
    _Float16* feat2 = feat1;   // feat1 dead after spmm1; reuse for layer 2

    // --- CSR build ---
    hipMemsetAsync(deg, 0, (size_t)NNODES * 4, stream);
    hipMemsetAsync(cursor, 0, (size_t)NNODES * 4, stream);
    hist_kernel<<<(NEDGES + 255) / 256, 256, 0, stream>>>(dst, deg);
    scan_kernel<<<1, 1024, 0, stream>>>(deg, offs);
    scatter_kernel<<<(NEDGES + 255) / 256, 256, 0, stream>>>(src, dst, offs, cursor, ssorted);

    // --- weight conversions ---
    convert_wt_kernel<<<(256 * 256 + 255) / 256, 256, 0, stream>>>(W1, W1hi, W1lo, 256, 256);
    convert_wt_kernel<<<(256 * 64 + 255) / 256, 256, 0, stream>>>(W2, W2hi, W2lo, 256, 64);

    // --- Layer 1: GEMM (inline split of fp32 x, fp16 out) + fused el/er ---
    gemm_mfma_kernel<128, false, true><<<dim3(256 / 128, (NNODES + 127) / 128), 256, 0, stream>>>(
        x, nullptr, nullptr, W1hi, W1lo, feat1, al1, ar1, el1, er1, NNODES, 256, 256);
    alpha1_kernel<<<NNODES / 4, 256, 0, stream>>>(
        (const float4*)el1, (const float4*)er1, offs, ssorted, (float4*)alpha1);
    spmm1_kernel<<<NNODES, 256, 0, stream>>>(
        (const half4*)feat1, alpha1, offs, ssorted, h1hi, h1lo);

    // --- Layer 2 ---
    gemm_mfma_kernel<64, true, false><<<dim3(64 / 64, (NNODES + 127) / 128), 256, 0, stream>>>(
        nullptr, h1hi, h1lo, W2hi, W2lo, feat2, nullptr, nullptr, nullptr, nullptr, NNODES, 64, 256);
    elr2_kernel<<<NNODES, 64, 0, stream>>>(feat2, al2, ar2, el2, er2);
    alpha2_kernel<<<NNODES / 4, 256, 0, stream>>>(el2, er2, offs, ssorted, alpha2);
    spmm2_kernel<<<NNODES, 256, 0, stream>>>(
        (const half4*)feat2, alpha2, offs, ssorted, (float4*)out);
}

// Round 6
// 457.098 us; speedup vs baseline: 1.5103x; 1.1708x over previous
//
#include <hip/hip_runtime.h>
#include <math.h>

#define NNODES 50000
#define NEDGES 800000
#define INDIM 256
#define HID 64
#define HEADS 4
#define OUTDIM 64
#define NEG_SLOPE 0.2f
#define NB ((NNODES + 1023) / 1024)   // 49 scan blocks

typedef __attribute__((ext_vector_type(8))) short short8;   // 8 bf16 = 4 VGPRs
typedef __attribute__((ext_vector_type(8))) unsigned short ushort8;
typedef __attribute__((ext_vector_type(4))) float f32x4;
typedef _Float16 __attribute__((ext_vector_type(4))) half4;

__device__ inline unsigned short bf16_rtn(float f) {
    unsigned int u = __float_as_uint(f);
    unsigned int r = u + 0x7fffu + ((u >> 16) & 1u);
    return (unsigned short)(r >> 16);
}
__device__ inline float bf16_to_f32(unsigned short h) {
    return __uint_as_float((unsigned int)h << 16);
}

// ---------------- CSR build ----------------

__global__ __launch_bounds__(256) void hist_kernel(const int* __restrict__ dst,
                                                   int* __restrict__ deg) {
    int i = blockIdx.x * 256 + threadIdx.x;
    if (i < NEDGES) atomicAdd(&deg[dst[i]], 1);
}

// Multi-block scan, stage 1: per-block (1024 elems) sum.
__global__ __launch_bounds__(256) void bsum_kernel(const int* __restrict__ deg,
                                                   int* __restrict__ bsums) {
    int b = blockIdx.x, t = threadIdx.x;
    int base = b * 1024 + t * 4;
    int s = 0;
    #pragma unroll
    for (int e = 0; e < 4; ++e) { int i = base + e; if (i < NNODES) s += deg[i]; }
    #pragma unroll
    for (int o = 32; o; o >>= 1) s += __shfl_xor(s, o);
    __shared__ int ws[4];
    int lane = t & 63, wid = t >> 6;
    if (lane == 0) ws[wid] = s;
    __syncthreads();
    if (t == 0) bsums[b] = ws[0] + ws[1] + ws[2] + ws[3];
}

// Stage 2: each block re-derives its global offset from bsums (NB<=64 fits one
// wave), scans its own 1024 elems, writes offs coalesced.
__global__ __launch_bounds__(256) void scan_write_kernel(const int* __restrict__ deg,
                                                         const int* __restrict__ bsums,
                                                         int* __restrict__ offs) {
    int b = blockIdx.x, t = threadIdx.x;
    int lane = t & 63, wid = t >> 6;
    int bv = (lane < b) ? bsums[lane] : 0;    // b <= NB-1 < 64
    #pragma unroll
    for (int o = 32; o; o >>= 1) bv += __shfl_xor(bv, o);  // block global offset
    int base = b * 1024 + t * 4;
    int v[4]; int tsum = 0;
    #pragma unroll
    for (int e = 0; e < 4; ++e) {
        int i = base + e;
        v[e] = (i < NNODES) ? deg[i] : 0;
        tsum += v[e];
    }
    int p = tsum;
    #pragma unroll
    for (int o = 1; o < 64; o <<= 1) { int u = __shfl_up(p, o); if (lane >= o) p += u; }
    __shared__ int ws[4];
    if (lane == 63) ws[wid] = p;
    __syncthreads();
    int woff = 0;
    for (int i = 0; i < wid; ++i) woff += ws[i];
    int run = bv + woff + p - tsum;           // exclusive prefix for this thread
    #pragma unroll
    for (int e = 0; e < 4; ++e) {
        int i = base + e;
        if (i < NNODES) { offs[i] = run; run += v[e]; }
    }
    if (b == 0 && t == 0) offs[NNODES] = NEDGES;
}

__global__ __launch_bounds__(256) void scatter_kernel(const int* __restrict__ src,
                                                      const int* __restrict__ dst,
                                                      const int* __restrict__ offs,
                                                      int* __restrict__ cursor,
                                                      int* __restrict__ ssorted) {
    int i = blockIdx.x * 256 + threadIdx.x;
    if (i < NEDGES) {
        int d = dst[i];
        int pos = offs[d] + atomicAdd(&cursor[d], 1);
        ssorted[pos] = src[i];
    }
}

// ---------------- weight transpose+split ----------------
// W [K][N] row-major -> transposed split Wt_hi/Wt_lo [N][K]

__global__ __launch_bounds__(256) void convert_wt_kernel(const float* __restrict__ W,
                                                         unsigned short* __restrict__ hi,
                                                         unsigned short* __restrict__ lo,
                                                         int K, int N) {
    int idx = blockIdx.x * 256 + threadIdx.x;
    if (idx >= K * N) return;
    int k = idx / N, n = idx - k * N;
    float v = W[idx];
    unsigned short h = bf16_rtn(v);
    hi[n * K + k] = h;
    lo[n * K + k] = bf16_rtn(v - bf16_to_f32(h));
}

// ---------------- split-bf16 MFMA GEMM ----------------
// C[M,N] = A @ Bt^T with Bt [N][K] pre-split bf16. A either fp32 [M,K]
// (SPLITA=false, split inline during staging) or pre-split hi/lo bf16.
// BM=128, BK=32, 4 waves 2x2, 3 MFMA products (hh, hl, lh). C stored fp16.
// ELR (BN=128 only): each wave's 64 cols = one head -> fused el/er epilogue.

template <int BN, bool SPLITA, bool ELR>
__global__ __launch_bounds__(256) void gemm_mfma_kernel(
        const float* __restrict__ Af,
        const unsigned short* __restrict__ Ahi, const unsigned short* __restrict__ Alo,
        const unsigned short* __restrict__ Bthi, const unsigned short* __restrict__ Btlo,
        _Float16* __restrict__ C,
        const float* __restrict__ al, const float* __restrict__ ar,
        float* __restrict__ el, float* __restrict__ er,
        int M, int N, int K) {
    constexpr int NT = BN / 32;       // n-tiles per wave
    constexpr int PB = BN / 64;       // B staging passes
    __shared__ unsigned short As_hi[128 * 40], As_lo[128 * 40];
    __shared__ unsigned short Bs_hi[BN * 40], Bs_lo[BN * 40];
    int t = threadIdx.x;
    int lane = t & 63, w = t >> 6;
    int wm = w >> 1, wn = w & 1;
    int lr = lane & 15, quad = lane >> 4;
    int m0 = blockIdx.y * 128, n0 = blockIdx.x * BN;

    f32x4 acc[4][NT];
    #pragma unroll
    for (int i = 0; i < 4; ++i)
        #pragma unroll
        for (int j = 0; j < NT; ++j) acc[i][j] = (f32x4){0.f, 0.f, 0.f, 0.f};

    int srow = t >> 2, schunk = t & 3;  // staging: row / 8-elem chunk

    for (int kk = 0; kk < K; kk += 32) {
        uint4 rah[2], ral[2], rbh[PB], rbl[PB];
        float4 fa[2][2];
        #pragma unroll
        for (int p = 0; p < 2; ++p) {
            int row = srow + p * 64;
            int gr = m0 + row;
            if (SPLITA) {
                if (gr < M) {
                    size_t off = (size_t)gr * K + kk + schunk * 8;
                    rah[p] = *(const uint4*)(Ahi + off);
                    ral[p] = *(const uint4*)(Alo + off);
                } else {
                    rah[p] = make_uint4(0, 0, 0, 0);
                    ral[p] = make_uint4(0, 0, 0, 0);
                }
            } else {
                if (gr < M) {
                    size_t off = (size_t)gr * K + kk + schunk * 8;
                    fa[p][0] = *(const float4*)(Af + off);
                    fa[p][1] = *(const float4*)(Af + off + 4);
                } else {
                    fa[p][0] = make_float4(0.f, 0.f, 0.f, 0.f);
                    fa[p][1] = make_float4(0.f, 0.f, 0.f, 0.f);
                }
            }
        }
        #pragma unroll
        for (int p = 0; p < PB; ++p) {
            int row = srow + p * 64;
            size_t off = (size_t)(n0 + row) * K + kk + schunk * 8;
            rbh[p] = *(const uint4*)(Bthi + off);
            rbl[p] = *(const uint4*)(Btlo + off);
        }
        __syncthreads();
        #pragma unroll
        for (int p = 0; p < 2; ++p) {
            int row = srow + p * 64;
            if (SPLITA) {
                *(uint4*)(As_hi + row * 40 + schunk * 8) = rah[p];
                *(uint4*)(As_lo + row * 40 + schunk * 8) = ral[p];
            } else {
                float v[8] = {fa[p][0].x, fa[p][0].y, fa[p][0].z, fa[p][0].w,
                              fa[p][1].x, fa[p][1].y, fa[p][1].z, fa[p][1].w};
                ushort8 hv, lv;
                #pragma unroll
                for (int e = 0; e < 8; ++e) {
                    unsigned short h = bf16_rtn(v[e]);
                    hv[e] = (short)h;
                    lv[e] = (short)bf16_rtn(v[e] - bf16_to_f32(h));
                }
                *(ushort8*)(As_hi + row * 40 + schunk * 8) = hv;
                *(ushort8*)(As_lo + row * 40 + schunk * 8) = lv;
            }
        }
        #pragma unroll
        for (int p = 0; p < PB; ++p) {
            int row = srow + p * 64;
            *(uint4*)(Bs_hi + row * 40 + schunk * 8) = rbh[p];
            *(uint4*)(Bs_lo + row * 40 + schunk * 8) = rbl[p];
        }
        __syncthreads();

        short8 ah[4], alo[4], bh[NT], blo[NT];
        #pragma unroll
        for (int i = 0; i < 4; ++i) {
            int r = wm * 64 + i * 16 + lr;
            ah[i]  = *(const short8*)(As_hi + r * 40 + quad * 8);
            alo[i] = *(const short8*)(As_lo + r * 40 + quad * 8);
        }
        #pragma unroll
        for (int j = 0; j < NT; ++j) {
            int r = wn * NT * 16 + j * 16 + lr;
            bh[j]  = *(const short8*)(Bs_hi + r * 40 + quad * 8);
            blo[j] = *(const short8*)(Bs_lo + r * 40 + quad * 8);
        }
        #pragma unroll
        for (int i = 0; i < 4; ++i)
            #pragma unroll
            for (int j = 0; j < NT; ++j) {
                acc[i][j] = __builtin_amdgcn_mfma_f32_16x16x32_bf16(ah[i], bh[j], acc[i][j], 0, 0, 0);
                acc[i][j] = __builtin_amdgcn_mfma_f32_16x16x32_bf16(ah[i], blo[j], acc[i][j], 0, 0, 0);
                acc[i][j] = __builtin_amdgcn_mfma_f32_16x16x32_bf16(alo[i], bh[j], acc[i][j], 0, 0, 0);
            }
        __syncthreads();
    }
    #pragma unroll
    for (int i = 0; i < 4; ++i) {
        #pragma unroll
        for (int r = 0; r < 4; ++r) {
            int row = m0 + wm * 64 + i * 16 + quad * 4 + r;
            if (row < M) {
                #pragma unroll
                for (int j = 0; j < NT; ++j)
                    C[(size_t)row * N + n0 + wn * NT * 16 + j * 16 + lr] =
                        (_Float16)acc[i][j][r];
            }
        }
    }
    if (ELR) {
        // wave (wm,wn) covers head h = n0/64 + wn, rows [m0+wm*64, +64)
        int h = n0 / 64 + wn;
        float alh[NT], arh[NT];
        #pragma unroll
        for (int j = 0; j < NT; ++j) {
            alh[j] = al[h * 64 + j * 16 + lr];
            arh[j] = ar[h * 64 + j * 16 + lr];
        }
        #pragma unroll
        for (int i = 0; i < 4; ++i) {
            #pragma unroll
            for (int r = 0; r < 4; ++r) {
                float pel = 0.f, per = 0.f;
                #pragma unroll
                for (int j = 0; j < NT; ++j) {
                    pel = fmaf(acc[i][j][r], alh[j], pel);
                    per = fmaf(acc[i][j][r], arh[j], per);
                }
                #pragma unroll
                for (int o = 1; o < 16; o <<= 1) {
                    pel += __shfl_xor(pel, o);
                    per += __shfl_xor(per, o);
                }
                if (lr == 0) {
                    int row = m0 + wm * 64 + i * 16 + quad * 4 + r;
                    if (row < M) {
                        el[row * HEADS + h] = pel;
                        er[row * HEADS + h] = per;
                    }
                }
            }
        }
    }
}

// ---------------- layer-2 attention dot products ----------------

__global__ __launch_bounds__(64) void elr2_kernel(const _Float16* __restrict__ feat,
                                                  const float* __restrict__ al,
                                                  const float* __restrict__ ar,
                                                  float* __restrict__ el,
                                                  float* __restrict__ er) {
    int n = blockIdx.x, d = threadIdx.x;
    float f = (float)feat[(size_t)n * 64 + d];
    float a = f * al[d], b = f * ar[d];
    #pragma unroll
    for (int o = 32; o; o >>= 1) { a += __shfl_xor(a, o); b += __shfl_xor(b, o); }
    if (d == 0) { el[n] = a; er[n] = b; }
}

// ---------------- softmax weights (alpha) per edge ----------------

__global__ __launch_bounds__(256) void alpha1_kernel(const float4* __restrict__ el,
                                                     const float4* __restrict__ er,
                                                     const int* __restrict__ offs,
                                                     const int* __restrict__ ssorted,
                                                     float4* __restrict__ alpha) {
    int n = blockIdx.x * 4 + (threadIdx.x >> 6);
    int l = threadIdx.x & 63;
    int start = offs[n], end = offs[n + 1];
    if (start == end) return;
    float4 ern = er[n];
    float m0 = -INFINITY, m1 = -INFINITY, m2 = -INFINITY, m3 = -INFINITY;
    float s0 = 0.f, s1 = 0.f, s2 = 0.f, s3 = 0.f;
    for (int base = start; base + l < end; base += 64) {
        int sj = ssorted[base + l];
        float4 ev = el[sj];
        float e0 = ev.x + ern.x; e0 = e0 > 0.f ? e0 : NEG_SLOPE * e0;
        float e1 = ev.y + ern.y; e1 = e1 > 0.f ? e1 : NEG_SLOPE * e1;
        float e2 = ev.z + ern.z; e2 = e2 > 0.f ? e2 : NEG_SLOPE * e2;
        float e3 = ev.w + ern.w; e3 = e3 > 0.f ? e3 : NEG_SLOPE * e3;
        float nm;
        nm = fmaxf(m0, e0); s0 = (m0 == nm ? s0 : s0 * __expf(m0 - nm)) + __expf(e0 - nm); m0 = nm;
        nm = fmaxf(m1, e1); s1 = (m1 == nm ? s1 : s1 * __expf(m1 - nm)) + __expf(e1 - nm); m1 = nm;
        nm = fmaxf(m2, e2); s2 = (m2 == nm ? s2 : s2 * __expf(m2 - nm)) + __expf(e2 - nm); m2 = nm;
        nm = fmaxf(m3, e3); s3 = (m3 == nm ? s3 : s3 * __expf(m3 - nm)) + __expf(e3 - nm); m3 = nm;
    }
    #pragma unroll
    for (int o = 1; o < 64; o <<= 1) {
        float om, os, nm, sa, sb;
        om = __shfl_xor(m0, o); os = __shfl_xor(s0, o); nm = fmaxf(m0, om);
        sa = (m0 == nm) ? s0 : s0 * __expf(m0 - nm); sb = (om == nm) ? os : os * __expf(om - nm);
        m0 = nm; s0 = sa + sb;
        om = __shfl_xor(m1, o); os = __shfl_xor(s1, o); nm = fmaxf(m1, om);
        sa = (m1 == nm) ? s1 : s1 * __expf(m1 - nm); sb = (om == nm) ? os : os * __expf(om - nm);
        m1 = nm; s1 = sa + sb;
        om = __shfl_xor(m2, o); os = __shfl_xor(s2, o); nm = fmaxf(m2, om);
        sa = (m2 == nm) ? s2 : s2 * __expf(m2 - nm); sb = (om == nm) ? os : os * __expf(om - nm);
        m2 = nm; s2 = sa + sb;
        om = __shfl_xor(m3, o); os = __shfl_xor(s3, o); nm = fmaxf(m3, om);
        sa = (m3 == nm) ? s3 : s3 * __expf(m3 - nm); sb = (om == nm) ? os : os * __expf(om - nm);
        m3 = nm; s3 = sa + sb;
    }
    float r0 = 1.f / s0, r1 = 1.f / s1, r2 = 1.f / s2, r3 = 1.f / s3;
    for (int base = start; base + l < end; base += 64) {
        int sj = ssorted[base + l];
        float4 ev = el[sj];
        float e0 = ev.x + ern.x; e0 = e0 > 0.f ? e0 : NEG_SLOPE * e0;
        float e1 = ev.y + ern.y; e1 = e1 > 0.f ? e1 : NEG_SLOPE * e1;
        float e2 = ev.z + ern.z; e2 = e2 > 0.f ? e2 : NEG_SLOPE * e2;
        float e3 = ev.w + ern.w; e3 = e3 > 0.f ? e3 : NEG_SLOPE * e3;
        float4 a;
        a.x = __expf(e0 - m0) * r0;
        a.y = __expf(e1 - m1) * r1;
        a.z = __expf(e2 - m2) * r2;
        a.w = __expf(e3 - m3) * r3;
        alpha[base + l] = a;
    }
}

__global__ __launch_bounds__(256) void alpha2_kernel(const float* __restrict__ el,
                                                     const float* __restrict__ er,
                                                     const int* __restrict__ offs,
                                                     const int* __restrict__ ssorted,
                                                     float* __restrict__ alpha) {
    int n = blockIdx.x * 4 + (threadIdx.x >> 6);
    int l = threadIdx.x & 63;
    int start = offs[n], end = offs[n + 1];
    if (start == end) return;
    float ern = er[n];
    float m = -INFINITY, s = 0.f;
    for (int base = start; base + l < end; base += 64) {
        int sj = ssorted[base + l];
        float e = el[sj] + ern; e = e > 0.f ? e : NEG_SLOPE * e;
        float nm = fmaxf(m, e);
        s = (m == nm ? s : s * __expf(m - nm)) + __expf(e - nm);
        m = nm;
    }
    #pragma unroll
    for (int o = 1; o < 64; o <<= 1) {
        float om = __shfl_xor(m, o), os = __shfl_xor(s, o);
        float nm = fmaxf(m, om);
        float sa = (m == nm) ? s : s * __expf(m - nm);
        float sb = (om == nm) ? os : os * __expf(om - nm);
        m = nm; s = sa + sb;
    }
    float r = 1.f / s;
    for (int base = start; base + l < end; base += 64) {
        int sj = ssorted[base + l];
        float e = el[sj] + ern; e = e > 0.f ? e : NEG_SLOPE * e;
        alpha[base + l] = __expf(e - m) * r;
    }
}

// ---------------- weighted aggregation (SpMM), fp16 feature gather ----------
// Layer 1: block = 1 node, 4 waves, x4 unroll -> 16 rows (512B each) in
// flight. Lane l holds cols 4l..4l+3 (half4 = 8B). Emits h1 split-bf16.

__global__ __launch_bounds__(256) void spmm1_kernel(const half4* __restrict__ feat,
                                                    const float* __restrict__ alpha,
                                                    const int* __restrict__ offs,
                                                    const int* __restrict__ ssorted,
                                                    unsigned short* __restrict__ h1hi,
                                                    unsigned short* __restrict__ h1lo) {
    __shared__ float4 red[3][64];
    int n = blockIdx.x;
    int g = threadIdx.x >> 6, l = threadIdx.x & 63;
    int h = l >> 4;
    int start = offs[n], end = offs[n + 1];
    float4 acc = {0.f, 0.f, 0.f, 0.f};
    int pos = start + g;
    for (; pos + 12 < end; pos += 16) {
        int s0 = ssorted[pos], s1 = ssorted[pos + 4],
            s2 = ssorted[pos + 8], s3 = ssorted[pos + 12];
        float a0 = alpha[pos * 4 + h], a1 = alpha[(pos + 4) * 4 + h],
              a2 = alpha[(pos + 8) * 4 + h], a3 = alpha[(pos + 12) * 4 + h];
        half4 f0 = feat[(size_t)s0 * 64 + l];
        half4 f1 = feat[(size_t)s1 * 64 + l];
        half4 f2 = feat[(size_t)s2 * 64 + l];
        half4 f3 = feat[(size_t)s3 * 64 + l];
        acc.x = fmaf(a0, (float)f0[0], acc.x); acc.y = fmaf(a0, (float)f0[1], acc.y);
        acc.z = fmaf(a0, (float)f0[2], acc.z); acc.w = fmaf(a0, (float)f0[3], acc.w);
        acc.x = fmaf(a1, (float)f1[0], acc.x); acc.y = fmaf(a1, (float)f1[1], acc.y);
        acc.z = fmaf(a1, (float)f1[2], acc.z); acc.w = fmaf(a1, (float)f1[3], acc.w);
        acc.x = fmaf(a2, (float)f2[0], acc.x); acc.y = fmaf(a2, (float)f2[1], acc.y);
        acc.z = fmaf(a2, (float)f2[2], acc.z); acc.w = fmaf(a2, (float)f2[3], acc.w);
        acc.x = fmaf(a3, (float)f3[0], acc.x); acc.y = fmaf(a3, (float)f3[1], acc.y);
        acc.z = fmaf(a3, (float)f3[2], acc.z); acc.w = fmaf(a3, (float)f3[3], acc.w);
    }
    for (; pos < end; pos += 4) {
        int s = ssorted[pos];
        float a = alpha[pos * 4 + h];
        half4 f = feat[(size_t)s * 64 + l];
        acc.x = fmaf(a, (float)f[0], acc.x);
        acc.y = fmaf(a, (float)f[1], acc.y);
        acc.z = fmaf(a, (float)f[2], acc.z);
        acc.w = fmaf(a, (float)f[3], acc.w);
    }
    if (g) red[g - 1][l] = acc;
    __syncthreads();
    if (!g) {
        float4 b0 = red[0][l], b1 = red[1][l], b2 = red[2][l];
        acc.x += b0.x + b1.x + b2.x;
        acc.y += b0.y + b1.y + b2.y;
        acc.z += b0.z + b1.z + b2.z;
        acc.w += b0.w + b1.w + b2.w;
        acc.x = acc.x > 0.f ? acc.x : __expf(acc.x) - 1.f;   // ELU
        acc.y = acc.y > 0.f ? acc.y : __expf(acc.y) - 1.f;
        acc.z = acc.z > 0.f ? acc.z : __expf(acc.z) - 1.f;
        acc.w = acc.w > 0.f ? acc.w : __expf(acc.w) - 1.f;
        unsigned short h0 = bf16_rtn(acc.x), h1 = bf16_rtn(acc.y),
                       h2 = bf16_rtn(acc.z), h3 = bf16_rtn(acc.w);
        ushort4 hv = make_ushort4(h0, h1, h2, h3);
        ushort4 lv = make_ushort4(bf16_rtn(acc.x - bf16_to_f32(h0)),
                                  bf16_rtn(acc.y - bf16_to_f32(h1)),
                                  bf16_rtn(acc.z - bf16_to_f32(h2)),
                                  bf16_rtn(acc.w - bf16_to_f32(h3)));
        *(ushort4*)&h1hi[(size_t)n * 256 + l * 4] = hv;
        *(ushort4*)&h1lo[(size_t)n * 256 + l * 4] = lv;
    }
}

// Layer 2: 16 subgroups of 16 lanes, x2 unroll -> 32 rows (128B) in flight.

__global__ __launch_bounds__(256) void spmm2_kernel(const half4* __restrict__ feat,
                                                    const float* __restrict__ alpha,
                                                    const int* __restrict__ offs,
                                                    const int* __restrict__ ssorted,
                                                    float4* __restrict__ out) {
    __shared__ float4 red[3][16];
    int n = blockIdx.x;
    int g = threadIdx.x >> 6, l = threadIdx.x & 63;
    int sub = l >> 4, li = l & 15;
    int start = offs[n], end = offs[n + 1];
    float4 acc = {0.f, 0.f, 0.f, 0.f};
    int pos = start + g * 4 + sub;
    for (; pos + 16 < end; pos += 32) {
        int s0 = ssorted[pos], s1 = ssorted[pos + 16];
        float a0 = alpha[pos], a1 = alpha[pos + 16];
        half4 f0 = feat[(size_t)s0 * 16 + li];
        half4 f1 = feat[(size_t)s1 * 16 + li];
        acc.x = fmaf(a0, (float)f0[0], acc.x); acc.y = fmaf(a0, (float)f0[1], acc.y);
        acc.z = fmaf(a0, (float)f0[2], acc.z); acc.w = fmaf(a0, (float)f0[3], acc.w);
        acc.x = fmaf(a1, (float)f1[0], acc.x); acc.y = fmaf(a1, (float)f1[1], acc.y);
        acc.z = fmaf(a1, (float)f1[2], acc.z); acc.w = fmaf(a1, (float)f1[3], acc.w);
    }
    for (; pos < end; pos += 16) {
        int s = ssorted[pos];
        float a = alpha[pos];
        half4 f = feat[(size_t)s * 16 + li];
        acc.x = fmaf(a, (float)f[0], acc.x);
        acc.y = fmaf(a, (float)f[1], acc.y);
        acc.z = fmaf(a, (float)f[2], acc.z);
        acc.w = fmaf(a, (float)f[3], acc.w);
    }
    #pragma unroll
    for (int o = 16; o < 64; o <<= 1) {
        acc.x += __shfl_xor(acc.x, o);
        acc.y += __shfl_xor(acc.y, o);
        acc.z += __shfl_xor(acc.z, o);
        acc.w += __shfl_xor(acc.w, o);
    }
    if (g && sub == 0) red[g - 1][li] = acc;
    __syncthreads();
    if (!g && sub == 0) {
        float4 b0 = red[0][li], b1 = red[1][li], b2 = red[2][li];
        acc.x += b0.x + b1.x + b2.x;
        acc.y += b0.y + b1.y + b2.y;
        acc.z += b0.z + b1.z + b2.z;
        acc.w += b0.w + b1.w + b2.w;
        out[(size_t)n * 16 + li] = acc;
    }
}

// ---------------- launch ----------------

extern "C" void kernel_launch(void* const* d_in, const int* in_sizes, int n_in,
                              void* d_out, int out_size, void* d_ws, size_t ws_size,
                              hipStream_t stream) {
    const float* x   = (const float*)d_in[0];
    const int*   src = (const int*)d_in[1];
    const int*   dst = (const int*)d_in[2];
    const float* W1  = (const float*)d_in[3];
    const float* al1 = (const float*)d_in[4];
    const float* ar1 = (const float*)d_in[5];
    const float* W2  = (const float*)d_in[6];
    const float* al2 = (const float*)d_in[7];
    const float* ar2 = (const float*)d_in[8];
    float* out = (float*)d_out;

    char* ws = (char*)d_ws;
    size_t off = 0;
    auto alloc = [&](size_t bytes) -> void* {
        void* p = ws + off;
        off += (bytes + 255) & ~(size_t)255;
        return p;
    };
    _Float16* feat1 = (_Float16*)alloc((size_t)NNODES * 256 * 2);             // 25.6 MB
    unsigned short* h1hi = (unsigned short*)alloc((size_t)NNODES * 256 * 2);  // 25.6 MB
    unsigned short* h1lo = (unsigned short*)alloc((size_t)NNODES * 256 * 2);  // 25.6 MB
    unsigned short* W1hi = (unsigned short*)alloc((size_t)256 * 256 * 2);
    unsigned short* W1lo = (unsigned short*)alloc((size_t)256 * 256 * 2);
    unsigned short* W2hi = (unsigned short*)alloc((size_t)64 * 256 * 2);
    unsigned short* W2lo = (unsigned short*)alloc((size_t)64 * 256 * 2);
    float* el1    = (float*)alloc((size_t)NNODES * HEADS * 4);
    float* er1    = (float*)alloc((size_t)NNODES * HEADS * 4);
    float* el2    = (float*)alloc((size_t)NNODES * 4);
    float* er2    = (float*)alloc((size_t)NNODES * 4);
    float* alpha1 = (float*)alloc((size_t)NEDGES * HEADS * 4);                // 12.8 MB
    float* alpha2 = (float*)alloc((size_t)NEDGES * 4);                        // 3.2 MB
    int* deg      = (int*)alloc((size_t)NNODES * 4);
    int* cursor   = (int*)alloc((size_t)NNODES * 4);
    int* offs     = (int*)alloc((size_t)(NNODES + 1) * 4);
    int* bsums    = (int*)alloc((size_t)NB * 4);
    int* ssorted  = (int*)alloc((size_t)NEDGES * 4);
    _Float16* feat2 = feat1;   // feat1 dead after spmm1; reuse for layer 2

    // --- CSR build ---
    hipMemsetAsync(deg, 0, (size_t)NNODES * 4, stream);
    hipMemsetAsync(cursor, 0, (size_t)NNODES * 4, stream);
    hist_kernel<<<(NEDGES + 255) / 256, 256, 0, stream>>>(dst, deg);
    bsum_kernel<<<NB, 256, 0, stream>>>(deg, bsums);
    scan_write_kernel<<<NB, 256, 0, stream>>>(deg, bsums, offs);
    scatter_kernel<<<(NEDGES + 255) / 256, 256, 0, stream>>>(src, dst, offs, cursor, ssorted);

    // --- weight conversions ---
    convert_wt_kernel<<<(256 * 256 + 255) / 256, 256, 0, stream>>>(W1, W1hi, W1lo, 256, 256);
    convert_wt_kernel<<<(256 * 64 + 255) / 256, 256, 0, stream>>>(W2, W2hi, W2lo, 256, 64);

    // --- Layer 1: GEMM (inline split of fp32 x, fp16 out) + fused el/er ---
    gemm_mfma_kernel<128, false, true><<<dim3(256 / 128, (NNODES + 127) / 128), 256, 0, stream>>>(
        x, nullptr, nullptr, W1hi, W1lo, feat1, al1, ar1, el1, er1, NNODES, 256, 256);
    alpha1_kernel<<<NNODES / 4, 256, 0, stream>>>(
        (const float4*)el1, (const float4*)er1, offs, ssorted, (float4*)alpha1);
    spmm1_kernel<<<NNODES, 256, 0, stream>>>(
        (const half4*)feat1, alpha1, offs, ssorted, h1hi, h1lo);

    // --- Layer 2 ---
    gemm_mfma_kernel<64, true, false><<<dim3(64 / 64, (NNODES + 127) / 128), 256, 0, stream>>>(
        nullptr, h1hi, h1lo, W2hi, W2lo, feat2, nullptr, nullptr, nullptr, nullptr, NNODES, 64, 256);
    elr2_kernel<<<NNODES, 64, 0, stream>>>(feat2, al2, ar2, el2, er2);
    alpha2_kernel<<<NNODES / 4, 256, 0, stream>>>(el2, er2, offs, ssorted, alpha2);
    spmm2_kernel<<<NNODES, 256, 0, stream>>>(
        (const half4*)feat2, alpha2, offs, ssorted, (float4*)out);
}